// Round 2
// baseline (7241.038 us; speedup 1.0000x reference)
//
#include <hip/hip_runtime.h>
#include <math.h>

#define NODE 5
#define TT 512
#define NBATCH 8192
#define NB 16            // batch elems per block
#define MR (NB*NODE)     // 80 rows
#define LDK 128          // row stride (halfs); XOR swizzle handles banks
#define TB 32
#define XS_DIM 325
#define H2 256
#define EPS 1e-5f

typedef _Float16 h16;
typedef __attribute__((ext_vector_type(8))) _Float16 half8;
typedef __attribute__((ext_vector_type(4))) _Float16 h16x4;
typedef __attribute__((ext_vector_type(2))) _Float16 half2v;
typedef __attribute__((ext_vector_type(4))) float float4v;

// XOR-swizzle: 16B-chunk index (bits 3..6 of half-col) XOR'd with row&7.
// Bijective within each row; keeps 16B-chunk contiguity/alignment. Applied
// to EVERY sg/sh access (swizzle both sides or neither).
__device__ __forceinline__ int swz(int row, int hc) {
    return row*LDK + (hc ^ ((row & 7) << 3));
}

// ---------------------------------------------------------------------------
// RNN kernel, 512-thread blocks (8 waves). Per step, 3 GCN layers as MFMA
// GEMMs (M=80, f16 in / f32 acc), node-mix (5x5, A in {0,1}) as VALU passes.
// Swapped MFMA operands (W^T as A-op, act as B-op) -> packed b64 epilogue
// stores. Each wave owns ONE 16-feature tile per layer (8 tiles for the
// 128-wide layers; the 64-wide L3 splits mt ranges across wave pairs), so
// the barrier-to-barrier critical path is ~half of the 4-wave version.
// ---------------------------------------------------------------------------
__global__ __launch_bounds__(512, 4) void rnn_kernel(
    const float* __restrict__ x, const float* __restrict__ adj,
    const float* __restrict__ W0, const float* __restrict__ b0,
    const float* __restrict__ W1, const float* __restrict__ b1,
    const float* __restrict__ W2, const float* __restrict__ b2,
    float* __restrict__ xs)
{
    __shared__ __align__(16) h16 sg[MR*LDK];          // 20480 B (mixed / B-operand)
    __shared__ __align__(16) h16 sh[MR*LDK];          // 20480 B (raw layer output)
    __shared__ h16 sx[2][NB][NODE][33];               // 10560 B (x chunks, dbuf)
    __shared__ float sxg[MR];                         //   320 B (mixed x for L1)

    const int tid  = threadIdx.x;
    const int lane = tid & 63;
    const int w    = tid >> 6;       // wave 0..7
    const int ln   = lane & 15;
    const int q    = lane >> 4;      // quad 0..3
    const int k0q  = q*8;
    const int bbase = blockIdx.x * NB;

    // ---- A = adj.T in registers (f32 + f16 copies; entries are 0/1) ----
    float af[NODE][NODE];
    h16   ah[NODE][NODE];
    #pragma unroll
    for (int i = 0; i < NODE; ++i)
        #pragma unroll
        for (int j = 0; j < NODE; ++j) {
            float v = adj[j*NODE + i];
            af[i][j] = v; ah[i][j] = (h16)v;
        }

    // ---- weight fragments (held in VGPRs): one 16-feat tile per wave ----
    // Loaded as A-frag of W^T: lane holds W[k = ks*32 + q*8 + j][feat tile].
    half8 wf0[2], wf1f[4], wf3[4];
    {
        int n1 = w*16 + ln;
        #pragma unroll
        for (int ks = 0; ks < 2; ++ks) {
            half8 f;
            #pragma unroll
            for (int j = 0; j < 8; ++j)
                f[j] = (h16)W0[(size_t)(1 + ks*32 + k0q + j)*128 + n1]; // rows 1..64
            wf0[ks] = f;
        }
        #pragma unroll
        for (int ks = 0; ks < 4; ++ks) {
            half8 f;
            #pragma unroll
            for (int j = 0; j < 8; ++j)
                f[j] = (h16)W1[(size_t)(ks*32 + k0q + j)*128 + n1];
            wf1f[ks] = f;
        }
        int n3 = (w&3)*16 + ln;
        #pragma unroll
        for (int ks = 0; ks < 4; ++ks) {
            half8 f;
            #pragma unroll
            for (int j = 0; j < 8; ++j)
                f[j] = (h16)W2[(size_t)(ks*32 + k0q + j)*64 + n3];
            wf3[ks] = f;
        }
    }
    // Per-lane epilogue constants indexed by OUTPUT FEATURE (swapped C-layout:
    // feat = tile*16 + q*4 + r, col = row80 = mt*16 + ln).
    float b0s[4], w0s[4], b1s[4], b2s[4];
    #pragma unroll
    for (int r = 0; r < 4; ++r) {
        int fi = w*16 + q*4 + r;
        b0s[r] = b0[fi];
        w0s[r] = W0[fi];             // W0 row 0 (x rank-1 term)
        b1s[r] = b1[fi];
        b2s[r] = b2[(w&3)*16 + q*4 + r];
    }
    const int m3lo = (w < 4) ? 0 : 3;    // L3 mt split across wave halves
    const int m3hi = (w < 4) ? 3 : 5;

    // ---- stage x chunk 0, zero initial state ----
    for (int i = tid; i < NB*NODE*TB; i += 512) {
        int t = i & 31; int rn = i >> 5; int n = rn % NODE; int e = rn / NODE;
        sx[0][e][n][t] = (h16)x[((size_t)(bbase+e)*NODE + n)*TT + t];
    }
    for (int i = tid; i < MR*64; i += 512) {
        int r = i >> 6, k = i & 63;
        sg[swz(r, k)] = (h16)0.f;
    }
    __syncthreads();
    if (tid < MR) {
        int b = tid / NODE, i = tid % NODE;
        float acc = 0.f;
        #pragma unroll
        for (int j = 0; j < NODE; ++j) acc += af[i][j]*(float)sx[0][b][j][0];
        sxg[tid] = acc;
    }
    __syncthreads();

    #pragma unroll 1
    for (int tc = 0; tc < TT/TB; ++tc) {
        if (tc+1 < TT/TB) {   // stage next chunk (read >=31 barriers later)
            for (int i = tid; i < NB*NODE*TB; i += 512) {
                int t = i & 31; int rn = i >> 5; int n = rn % NODE; int e = rn / NODE;
                sx[(tc+1)&1][e][n][t] =
                    (h16)x[((size_t)(bbase+e)*NODE + n)*TT + (tc+1)*TB + t];
            }
        }
        #pragma unroll 1
        for (int tt = 0; tt < TB; ++tt) {
            const int t = tc*TB + tt;
            // ---------------- L1: h1 = relu( gS @ W0' + x*w0r0 + b0 ) ------
            #pragma unroll
            for (int mt = 0; mt < 5; ++mt) {
                const int row = mt*16 + ln;
                half8 a0 = *(const half8*)&sg[swz(row, 0  + k0q)];
                half8 a1 = *(const half8*)&sg[swz(row, 32 + k0q)];
                float xg = sxg[row];
                float4v acc = {0.f,0.f,0.f,0.f};
                acc = __builtin_amdgcn_mfma_f32_16x16x32_f16(wf0[0], a0, acc, 0,0,0);
                acc = __builtin_amdgcn_mfma_f32_16x16x32_f16(wf0[1], a1, acc, 0,0,0);
                h16x4 o;
                #pragma unroll
                for (int r = 0; r < 4; ++r) {
                    float v = acc[r] + b0s[r] + xg*w0s[r];
                    o[r] = (h16)fmaxf(v, 0.f);
                }
                *(h16x4*)&sh[swz(row, w*16 + q*4)] = o;
            }
            __syncthreads();
            // ---------------- M1: g1 = A @ h1 (packed f16, 512 thr) -------
            {
                int b = tid >> 5, ko = tid & 31;
                const int hc = ko*4;
                half2v v[NODE][2];
                #pragma unroll
                for (int j = 0; j < NODE; ++j) {
                    const half2v* p = (const half2v*)&sh[swz(b*NODE+j, hc)];
                    v[j][0]=p[0]; v[j][1]=p[1];
                }
                #pragma unroll
                for (int i = 0; i < NODE; ++i) {
                    half2v a0={(h16)0,(h16)0}, a1=a0;
                    #pragma unroll
                    for (int j = 0; j < NODE; ++j) {
                        half2v aa = { ah[i][j], ah[i][j] };
                        a0 += aa*v[j][0]; a1 += aa*v[j][1];
                    }
                    half2v* po = (half2v*)&sg[swz(b*NODE+i, hc)];
                    po[0]=a0; po[1]=a1;
                }
            }
            __syncthreads();
            // ---------------- L2: h2 = relu( g1 @ W1 + b1 ) ---------------
            #pragma unroll
            for (int mt = 0; mt < 5; ++mt) {
                const int row = mt*16 + ln;
                half8 a[4];
                #pragma unroll
                for (int ks = 0; ks < 4; ++ks)
                    a[ks] = *(const half8*)&sg[swz(row, ks*32 + k0q)];
                float4v acc = {0.f,0.f,0.f,0.f};
                #pragma unroll
                for (int ks = 0; ks < 4; ++ks)
                    acc = __builtin_amdgcn_mfma_f32_16x16x32_f16(wf1f[ks], a[ks], acc, 0,0,0);
                h16x4 o;
                #pragma unroll
                for (int r = 0; r < 4; ++r)
                    o[r] = (h16)fmaxf(acc[r] + b1s[r], 0.f);
                *(h16x4*)&sh[swz(row, w*16 + q*4)] = o;
            }
            __syncthreads();
            // ---------------- M2: g2 = A @ h2 -----------------------------
            {
                int b = tid >> 5, ko = tid & 31;
                const int hc = ko*4;
                half2v v[NODE][2];
                #pragma unroll
                for (int j = 0; j < NODE; ++j) {
                    const half2v* p = (const half2v*)&sh[swz(b*NODE+j, hc)];
                    v[j][0]=p[0]; v[j][1]=p[1];
                }
                #pragma unroll
                for (int i = 0; i < NODE; ++i) {
                    half2v a0={(h16)0,(h16)0}, a1=a0;
                    #pragma unroll
                    for (int j = 0; j < NODE; ++j) {
                        half2v aa = { ah[i][j], ah[i][j] };
                        a0 += aa*v[j][0]; a1 += aa*v[j][1];
                    }
                    half2v* po = (half2v*)&sg[swz(b*NODE+i, hc)];
                    po[0]=a0; po[1]=a1;
                }
            }
            __syncthreads();
            // ---------------- L3: state = tanh( g2 @ W2 + b2 ) ------------
            #pragma unroll
            for (int mt = m3lo; mt < m3hi; ++mt) {
                const int row = mt*16 + ln;
                half8 a[4];
                #pragma unroll
                for (int ks = 0; ks < 4; ++ks)
                    a[ks] = *(const half8*)&sg[swz(row, ks*32 + k0q)];
                float4v acc = {0.f,0.f,0.f,0.f};
                #pragma unroll
                for (int ks = 0; ks < 4; ++ks)
                    acc = __builtin_amdgcn_mfma_f32_16x16x32_f16(wf3[ks], a[ks], acc, 0,0,0);
                h16x4 o;
                #pragma unroll
                for (int r = 0; r < 4; ++r) {
                    float z = acc[r] + b2s[r];
                    float e = __expf(-2.f*fabsf(z));
                    float th = copysignf((1.f - e)/(1.f + e), z);
                    o[r] = (h16)th;
                }
                *(h16x4*)&sh[swz(row, (w&3)*16 + q*4)] = o;
            }
            __syncthreads();
            // ------- M3: gS = A @ state (f32 acc) + xg for t+1 ------------
            if (tid < 256) {
                int b = tid >> 4, ko = tid & 15;
                const int hc = ko*4;
                float v[NODE][4];
                #pragma unroll
                for (int j = 0; j < NODE; ++j) {
                    h16x4 hv = *(const h16x4*)&sh[swz(b*NODE+j, hc)];
                    #pragma unroll
                    for (int c = 0; c < 4; ++c) v[j][c] = (float)hv[c];
                }
                #pragma unroll
                for (int i = 0; i < NODE; ++i) {
                    h16x4 o;
                    #pragma unroll
                    for (int c = 0; c < 4; ++c) {
                        float acc = 0.f;
                        #pragma unroll
                        for (int j = 0; j < NODE; ++j) acc += af[i][j]*v[j][c];
                        o[c] = (h16)acc;
                    }
                    *(h16x4*)&sg[swz(b*NODE+i, hc)] = o;
                }
            } else if (tid < 256 + MR) {
                int t2 = t + 1;
                if (t2 < TT) {
                    int tl = tid - 256;
                    int b = tl / NODE, i = tl % NODE;
                    int buf = (t2 >> 5) & 1, ti = t2 & 31;
                    float acc = 0.f;
                    #pragma unroll
                    for (int j = 0; j < NODE; ++j)
                        acc += af[i][j]*(float)sx[buf][b][j][ti];
                    sxg[tl] = acc;
                }
            }
            __syncthreads();
        }
    }

    // ---- epilogue: xs[b] = [x_end(5) | state(5*64)] (state is raw, in sh) ----
    if (tid < 256) {
        int e = tid >> 4, f = tid & 15;
        size_t ob = (size_t)(bbase+e)*XS_DIM;
        #pragma unroll
        for (int n = 0; n < NODE; ++n) {
            h16x4 hv = *(const h16x4*)&sh[swz(e*NODE+n, f*4)];
            #pragma unroll
            for (int c = 0; c < 4; ++c)
                xs[ob + 5 + n*64 + f*4 + c] = (float)hv[c];
        }
        if (f < NODE)
            xs[ob + f] = (float)sx[1][e][f][31];   // chunk 15 -> buf 1, t=511
    }
}

// ---------------------------------------------------------------------------
// Kernel B: h = relu(xs @ fc1_w + fc1_b) + per-column sum/sumsq for BN.
// ---------------------------------------------------------------------------
__global__ __launch_bounds__(256) void fc1_kernel(
    const float* __restrict__ xs, const float* __restrict__ fc1_w,
    const float* __restrict__ fc1_b, float* __restrict__ h,
    float* __restrict__ sums)
{
    __shared__ float s_xs[16*XS_DIM];
    const int tid = threadIdx.x;
    const int r0 = blockIdx.x * 16;
    for (int i = tid; i < 16*XS_DIM; i += 256)
        s_xs[i] = xs[(size_t)r0*XS_DIM + i];
    __syncthreads();

    float acc[16];
    #pragma unroll
    for (int r = 0; r < 16; ++r) acc[r] = 0.f;
    for (int k = 0; k < XS_DIM; ++k) {
        float wv = fc1_w[(size_t)k*H2 + tid];
        #pragma unroll
        for (int r = 0; r < 16; ++r) acc[r] += s_xs[r*XS_DIM + k]*wv;
    }
    float bb = fc1_b[tid];
    float ls = 0.f, lq = 0.f;
    #pragma unroll
    for (int r = 0; r < 16; ++r) {
        float v = fmaxf(acc[r] + bb, 0.f);
        h[(size_t)(r0+r)*H2 + tid] = v;
        ls += v; lq += v*v;
    }
    atomicAdd(&sums[tid], ls);
    atomicAdd(&sums[H2 + tid], lq);
}

// ---------------------------------------------------------------------------
// Kernel C: BN(train) normalize + fc2 + softmax. One wave per row.
// ---------------------------------------------------------------------------
__global__ __launch_bounds__(256) void head_kernel(
    const float* __restrict__ h, const float* __restrict__ sums,
    const float* __restrict__ gamma, const float* __restrict__ beta,
    const float* __restrict__ fc2_w, const float* __restrict__ fc2_b,
    float* __restrict__ out)
{
    const int lane = threadIdx.x & 63;
    const int r = blockIdx.x*4 + (threadIdx.x >> 6);
    const int c0 = lane*4;

    float4 hv = *(const float4*)&h[(size_t)r*H2 + c0];
    float hvv[4] = {hv.x, hv.y, hv.z, hv.w};
    float y[4];
    #pragma unroll
    for (int c = 0; c < 4; ++c) {
        int cc = c0 + c;
        float mean = sums[cc] * (1.f/NBATCH);
        float var  = sums[H2+cc]*(1.f/NBATCH) - mean*mean;
        float rstd = rsqrtf(var + EPS);
        y[c] = (hvv[c] - mean)*rstd*gamma[cc] + beta[cc];
    }
    float lg[7];
    #pragma unroll
    for (int j = 0; j < 7; ++j) {
        float p = 0.f;
        #pragma unroll
        for (int c = 0; c < 4; ++c) p += y[c]*fc2_w[(size_t)(c0+c)*7 + j];
        #pragma unroll
        for (int off = 32; off >= 1; off >>= 1) p += __shfl_xor(p, off, 64);
        lg[j] = p + fc2_b[j];
    }
    if (lane == 0) {
        float m = lg[0];
        #pragma unroll
        for (int j = 1; j < 7; ++j) m = fmaxf(m, lg[j]);
        float ev[7]; float s = 0.f;
        #pragma unroll
        for (int j = 0; j < 7; ++j) { ev[j] = expf(lg[j]-m); s += ev[j]; }
        float inv = 1.f/s;
        #pragma unroll
        for (int j = 0; j < 7; ++j) out[(size_t)r*7 + j] = ev[j]*inv;
    }
}

// ---------------------------------------------------------------------------
extern "C" void kernel_launch(void* const* d_in, const int* in_sizes, int n_in,
                              void* d_out, int out_size, void* d_ws, size_t ws_size,
                              hipStream_t stream)
{
    (void)in_sizes; (void)n_in; (void)out_size; (void)ws_size;
    const float* x     = (const float*)d_in[0];
    const float* adj   = (const float*)d_in[1];
    const float* W0    = (const float*)d_in[2];
    const float* b0    = (const float*)d_in[3];
    const float* W1    = (const float*)d_in[4];
    const float* b1    = (const float*)d_in[5];
    const float* W2    = (const float*)d_in[6];
    const float* b2    = (const float*)d_in[7];
    const float* fc1w  = (const float*)d_in[8];
    const float* fc1b  = (const float*)d_in[9];
    const float* gamma = (const float*)d_in[10];
    const float* beta  = (const float*)d_in[11];
    const float* fc2w  = (const float*)d_in[12];
    const float* fc2b  = (const float*)d_in[13];
    float* out = (float*)d_out;

    char* ws = (char*)d_ws;
    float* xs   = (float*)(ws);                                  // 8192*325 f32
    float* hbuf = (float*)(ws + 10649600);                       // 8192*256 f32
    float* sums = (float*)(ws + 10649600 + 8388608);             // 512 f32

    hipMemsetAsync(sums, 0, 512*sizeof(float), stream);
    rnn_kernel<<<NBATCH/NB, 512, 0, stream>>>(x, adj, W0, b0, W1, b1, W2, b2, xs);
    fc1_kernel<<<NBATCH/16, 256, 0, stream>>>(xs, fc1w, fc1b, hbuf, sums);
    head_kernel<<<NBATCH/4, 256, 0, stream>>>(hbuf, sums, gamma, beta, fc2w, fc2b, out);
}

// Round 3
// 3605.817 us; speedup vs baseline: 2.0082x; 2.0082x over previous
//
#include <hip/hip_runtime.h>
#include <math.h>

#define NODE 5
#define TT 512
#define NBATCH 8192
#define NB 16            // batch elems per block
#define MR (NB*NODE)     // 80 rows
#define LDK 128          // row stride (halfs); XOR swizzle handles banks
#define TB 32
#define XS_DIM 325
#define H2 256
#define EPS 1e-5f

typedef _Float16 h16;
typedef __attribute__((ext_vector_type(8))) _Float16 half8;
typedef __attribute__((ext_vector_type(4))) _Float16 h16x4;
typedef __attribute__((ext_vector_type(2))) _Float16 half2v;
typedef __attribute__((ext_vector_type(4))) float float4v;

// XOR-swizzle: half-col bits 3..5 XOR'd with row&7. Bijective per row; moves
// whole 8B/16B blocks so all used access widths stay contained & aligned.
// Applied to EVERY sg/sh access (swizzle both sides or neither).
__device__ __forceinline__ int swz(int row, int hc) {
    return row*LDK + (hc ^ ((row & 7) << 3));
}

// ---------------------------------------------------------------------------
// RNN kernel, 512-thread blocks (8 waves). Per step, 3 GCN layers as MFMA
// GEMMs (M=80, f16 in / f32 acc), node-mix (5x5) as packed-f16 VALU passes.
// Swapped MFMA operands (W^T as A-op, act as B-op) -> packed b64 epilogue
// stores. Each wave owns ONE 16-feature tile per layer.
// __launch_bounds__(512, 2): on this toolchain the 2nd arg scales with waves
// per block — (512,4) produced a 64-VGPR cap and catastrophic scratch spill
// (round 2: FETCH 15 GB). (512,2) => 4 waves/SIMD budget = 128 VGPRs, which
// the persistent state (~110) fits without spilling.
// ---------------------------------------------------------------------------
__global__ __launch_bounds__(512, 2) void rnn_kernel(
    const float* __restrict__ x, const float* __restrict__ adj,
    const float* __restrict__ W0, const float* __restrict__ b0,
    const float* __restrict__ W1, const float* __restrict__ b1,
    const float* __restrict__ W2, const float* __restrict__ b2,
    float* __restrict__ xs)
{
    __shared__ __align__(16) h16 sg[MR*LDK];          // 20480 B (mixed / B-operand)
    __shared__ __align__(16) h16 sh[MR*LDK];          // 20480 B (raw layer output)
    __shared__ h16 sx[2][NB][NODE][33];               // 10560 B (x chunks, dbuf)
    __shared__ float sxg[MR];                         //   320 B (mixed x for L1)

    const int tid  = threadIdx.x;
    const int lane = tid & 63;
    const int w    = tid >> 6;       // wave 0..7
    const int ln   = lane & 15;
    const int q    = lane >> 4;      // quad 0..3
    const int k0q  = q*8;
    const int bbase = blockIdx.x * NB;

    // ---- A = adj.T in registers: f32 (M3/sxg exact path) + duplicated
    //      half2v for the packed-f16 M1/M2 passes ----
    float  af[NODE][NODE];
    half2v ahp[NODE][NODE];
    #pragma unroll
    for (int i = 0; i < NODE; ++i)
        #pragma unroll
        for (int j = 0; j < NODE; ++j) {
            float v = adj[j*NODE + i];
            af[i][j] = v;
            h16 hv = (h16)v;
            half2v t; t[0] = hv; t[1] = hv;
            ahp[i][j] = t;
        }

    // ---- weight fragments (held in VGPRs): one 16-feat tile per wave ----
    // Loaded as A-frag of W^T: lane holds W[k = ks*32 + q*8 + j][feat tile].
    half8 wf0[2], wf1f[4], wf3[4];
    {
        int n1 = w*16 + ln;
        #pragma unroll
        for (int ks = 0; ks < 2; ++ks) {
            half8 f;
            #pragma unroll
            for (int j = 0; j < 8; ++j)
                f[j] = (h16)W0[(size_t)(1 + ks*32 + k0q + j)*128 + n1]; // rows 1..64
            wf0[ks] = f;
        }
        #pragma unroll
        for (int ks = 0; ks < 4; ++ks) {
            half8 f;
            #pragma unroll
            for (int j = 0; j < 8; ++j)
                f[j] = (h16)W1[(size_t)(ks*32 + k0q + j)*128 + n1];
            wf1f[ks] = f;
        }
        int n3 = (w&3)*16 + ln;
        #pragma unroll
        for (int ks = 0; ks < 4; ++ks) {
            half8 f;
            #pragma unroll
            for (int j = 0; j < 8; ++j)
                f[j] = (h16)W2[(size_t)(ks*32 + k0q + j)*64 + n3];
            wf3[ks] = f;
        }
    }
    // Per-lane epilogue constants indexed by OUTPUT FEATURE (swapped C-layout:
    // feat = tile*16 + q*4 + r, col = row80 = mt*16 + ln).
    float b0s[4], w0s[4], b1s[4], b2s[4];
    #pragma unroll
    for (int r = 0; r < 4; ++r) {
        int fi = w*16 + q*4 + r;
        b0s[r] = b0[fi];
        w0s[r] = W0[fi];             // W0 row 0 (x rank-1 term)
        b1s[r] = b1[fi];
        b2s[r] = b2[(w&3)*16 + q*4 + r];
    }
    const int m3lo = (w < 4) ? 0 : 3;    // L3 mt split across wave halves
    const int m3hi = (w < 4) ? 3 : 5;

    // ---- stage x chunk 0, zero initial state ----
    for (int i = tid; i < NB*NODE*TB; i += 512) {
        int t = i & 31; int rn = i >> 5; int n = rn % NODE; int e = rn / NODE;
        sx[0][e][n][t] = (h16)x[((size_t)(bbase+e)*NODE + n)*TT + t];
    }
    for (int i = tid; i < MR*64; i += 512) {
        int r = i >> 6, k = i & 63;
        sg[swz(r, k)] = (h16)0.f;
    }
    __syncthreads();
    if (tid < MR) {
        int b = tid / NODE, i = tid % NODE;
        float acc = 0.f;
        #pragma unroll
        for (int j = 0; j < NODE; ++j) acc += af[i][j]*(float)sx[0][b][j][0];
        sxg[tid] = acc;
    }
    __syncthreads();

    #pragma unroll 1
    for (int tc = 0; tc < TT/TB; ++tc) {
        if (tc+1 < TT/TB) {   // stage next chunk (read >=31 barriers later)
            for (int i = tid; i < NB*NODE*TB; i += 512) {
                int t = i & 31; int rn = i >> 5; int n = rn % NODE; int e = rn / NODE;
                sx[(tc+1)&1][e][n][t] =
                    (h16)x[((size_t)(bbase+e)*NODE + n)*TT + (tc+1)*TB + t];
            }
        }
        #pragma unroll 1
        for (int tt = 0; tt < TB; ++tt) {
            const int t = tc*TB + tt;
            // ---------------- L1: h1 = relu( gS @ W0' + x*w0r0 + b0 ) ------
            #pragma unroll
            for (int mt = 0; mt < 5; ++mt) {
                const int row = mt*16 + ln;
                half8 a0 = *(const half8*)&sg[swz(row, 0  + k0q)];
                half8 a1 = *(const half8*)&sg[swz(row, 32 + k0q)];
                float xg = sxg[row];
                float4v acc = {0.f,0.f,0.f,0.f};
                acc = __builtin_amdgcn_mfma_f32_16x16x32_f16(wf0[0], a0, acc, 0,0,0);
                acc = __builtin_amdgcn_mfma_f32_16x16x32_f16(wf0[1], a1, acc, 0,0,0);
                h16x4 o;
                #pragma unroll
                for (int r = 0; r < 4; ++r) {
                    float v = acc[r] + b0s[r] + xg*w0s[r];
                    o[r] = (h16)fmaxf(v, 0.f);
                }
                *(h16x4*)&sh[swz(row, w*16 + q*4)] = o;
            }
            __syncthreads();
            // ---------------- M1: g1 = A @ h1 (packed f16, b64 ops) -------
            {
                int b = tid >> 5, ko = tid & 31;
                const int hc = ko*4;
                half2v vlo[NODE], vhi[NODE];
                #pragma unroll
                for (int j = 0; j < NODE; ++j) {
                    h16x4 hv = *(const h16x4*)&sh[swz(b*NODE+j, hc)];
                    half2v lo; lo[0]=hv[0]; lo[1]=hv[1];
                    half2v hi; hi[0]=hv[2]; hi[1]=hv[3];
                    vlo[j]=lo; vhi[j]=hi;
                }
                #pragma unroll
                for (int i = 0; i < NODE; ++i) {
                    half2v a0={(h16)0,(h16)0}, a1=a0;
                    #pragma unroll
                    for (int j = 0; j < NODE; ++j) {
                        a0 += ahp[i][j]*vlo[j];
                        a1 += ahp[i][j]*vhi[j];
                    }
                    h16x4 o; o[0]=a0[0]; o[1]=a0[1]; o[2]=a1[0]; o[3]=a1[1];
                    *(h16x4*)&sg[swz(b*NODE+i, hc)] = o;
                }
            }
            __syncthreads();
            // ---------------- L2: h2 = relu( g1 @ W1 + b1 ) ---------------
            #pragma unroll
            for (int mt = 0; mt < 5; ++mt) {
                const int row = mt*16 + ln;
                half8 a[4];
                #pragma unroll
                for (int ks = 0; ks < 4; ++ks)
                    a[ks] = *(const half8*)&sg[swz(row, ks*32 + k0q)];
                float4v acc = {0.f,0.f,0.f,0.f};
                #pragma unroll
                for (int ks = 0; ks < 4; ++ks)
                    acc = __builtin_amdgcn_mfma_f32_16x16x32_f16(wf1f[ks], a[ks], acc, 0,0,0);
                h16x4 o;
                #pragma unroll
                for (int r = 0; r < 4; ++r)
                    o[r] = (h16)fmaxf(acc[r] + b1s[r], 0.f);
                *(h16x4*)&sh[swz(row, w*16 + q*4)] = o;
            }
            __syncthreads();
            // ---------------- M2: g2 = A @ h2 -----------------------------
            {
                int b = tid >> 5, ko = tid & 31;
                const int hc = ko*4;
                half2v vlo[NODE], vhi[NODE];
                #pragma unroll
                for (int j = 0; j < NODE; ++j) {
                    h16x4 hv = *(const h16x4*)&sh[swz(b*NODE+j, hc)];
                    half2v lo; lo[0]=hv[0]; lo[1]=hv[1];
                    half2v hi; hi[0]=hv[2]; hi[1]=hv[3];
                    vlo[j]=lo; vhi[j]=hi;
                }
                #pragma unroll
                for (int i = 0; i < NODE; ++i) {
                    half2v a0={(h16)0,(h16)0}, a1=a0;
                    #pragma unroll
                    for (int j = 0; j < NODE; ++j) {
                        a0 += ahp[i][j]*vlo[j];
                        a1 += ahp[i][j]*vhi[j];
                    }
                    h16x4 o; o[0]=a0[0]; o[1]=a0[1]; o[2]=a1[0]; o[3]=a1[1];
                    *(h16x4*)&sg[swz(b*NODE+i, hc)] = o;
                }
            }
            __syncthreads();
            // ---------------- L3: state = tanh( g2 @ W2 + b2 ) ------------
            #pragma unroll
            for (int mt = m3lo; mt < m3hi; ++mt) {
                const int row = mt*16 + ln;
                half8 a[4];
                #pragma unroll
                for (int ks = 0; ks < 4; ++ks)
                    a[ks] = *(const half8*)&sg[swz(row, ks*32 + k0q)];
                float4v acc = {0.f,0.f,0.f,0.f};
                #pragma unroll
                for (int ks = 0; ks < 4; ++ks)
                    acc = __builtin_amdgcn_mfma_f32_16x16x32_f16(wf3[ks], a[ks], acc, 0,0,0);
                h16x4 o;
                #pragma unroll
                for (int r = 0; r < 4; ++r) {
                    float z = acc[r] + b2s[r];
                    float e = __expf(-2.f*fabsf(z));
                    float th = copysignf((1.f - e)/(1.f + e), z);
                    o[r] = (h16)th;
                }
                *(h16x4*)&sh[swz(row, (w&3)*16 + q*4)] = o;
            }
            __syncthreads();
            // ------- M3: gS = A @ state (f32 acc) + xg for t+1 ------------
            if (tid < 256) {
                int b = tid >> 4, ko = tid & 15;
                const int hc = ko*4;
                float v[NODE][4];
                #pragma unroll
                for (int j = 0; j < NODE; ++j) {
                    h16x4 hv = *(const h16x4*)&sh[swz(b*NODE+j, hc)];
                    #pragma unroll
                    for (int c = 0; c < 4; ++c) v[j][c] = (float)hv[c];
                }
                #pragma unroll
                for (int i = 0; i < NODE; ++i) {
                    h16x4 o;
                    #pragma unroll
                    for (int c = 0; c < 4; ++c) {
                        float acc = 0.f;
                        #pragma unroll
                        for (int j = 0; j < NODE; ++j) acc += af[i][j]*v[j][c];
                        o[c] = (h16)acc;
                    }
                    *(h16x4*)&sg[swz(b*NODE+i, hc)] = o;
                }
            } else if (tid < 256 + MR) {
                int t2 = t + 1;
                if (t2 < TT) {
                    int tl = tid - 256;
                    int b = tl / NODE, i = tl % NODE;
                    int buf = (t2 >> 5) & 1, ti = t2 & 31;
                    float acc = 0.f;
                    #pragma unroll
                    for (int j = 0; j < NODE; ++j)
                        acc += af[i][j]*(float)sx[buf][b][j][ti];
                    sxg[tl] = acc;
                }
            }
            __syncthreads();
        }
    }

    // ---- epilogue: xs[b] = [x_end(5) | state(5*64)] (state is raw, in sh) ----
    if (tid < 256) {
        int e = tid >> 4, f = tid & 15;
        size_t ob = (size_t)(bbase+e)*XS_DIM;
        #pragma unroll
        for (int n = 0; n < NODE; ++n) {
            h16x4 hv = *(const h16x4*)&sh[swz(e*NODE+n, f*4)];
            #pragma unroll
            for (int c = 0; c < 4; ++c)
                xs[ob + 5 + n*64 + f*4 + c] = (float)hv[c];
        }
        if (f < NODE)
            xs[ob + f] = (float)sx[1][e][f][31];   // chunk 15 -> buf 1, t=511
    }
}

// ---------------------------------------------------------------------------
// Kernel B: h = relu(xs @ fc1_w + fc1_b) + per-column sum/sumsq for BN.
// ---------------------------------------------------------------------------
__global__ __launch_bounds__(256) void fc1_kernel(
    const float* __restrict__ xs, const float* __restrict__ fc1_w,
    const float* __restrict__ fc1_b, float* __restrict__ h,
    float* __restrict__ sums)
{
    __shared__ float s_xs[16*XS_DIM];
    const int tid = threadIdx.x;
    const int r0 = blockIdx.x * 16;
    for (int i = tid; i < 16*XS_DIM; i += 256)
        s_xs[i] = xs[(size_t)r0*XS_DIM + i];
    __syncthreads();

    float acc[16];
    #pragma unroll
    for (int r = 0; r < 16; ++r) acc[r] = 0.f;
    for (int k = 0; k < XS_DIM; ++k) {
        float wv = fc1_w[(size_t)k*H2 + tid];
        #pragma unroll
        for (int r = 0; r < 16; ++r) acc[r] += s_xs[r*XS_DIM + k]*wv;
    }
    float bb = fc1_b[tid];
    float ls = 0.f, lq = 0.f;
    #pragma unroll
    for (int r = 0; r < 16; ++r) {
        float v = fmaxf(acc[r] + bb, 0.f);
        h[(size_t)(r0+r)*H2 + tid] = v;
        ls += v; lq += v*v;
    }
    atomicAdd(&sums[tid], ls);
    atomicAdd(&sums[H2 + tid], lq);
}

// ---------------------------------------------------------------------------
// Kernel C: BN(train) normalize + fc2 + softmax. One wave per row.
// ---------------------------------------------------------------------------
__global__ __launch_bounds__(256) void head_kernel(
    const float* __restrict__ h, const float* __restrict__ sums,
    const float* __restrict__ gamma, const float* __restrict__ beta,
    const float* __restrict__ fc2_w, const float* __restrict__ fc2_b,
    float* __restrict__ out)
{
    const int lane = threadIdx.x & 63;
    const int r = blockIdx.x*4 + (threadIdx.x >> 6);
    const int c0 = lane*4;

    float4 hv = *(const float4*)&h[(size_t)r*H2 + c0];
    float hvv[4] = {hv.x, hv.y, hv.z, hv.w};
    float y[4];
    #pragma unroll
    for (int c = 0; c < 4; ++c) {
        int cc = c0 + c;
        float mean = sums[cc] * (1.f/NBATCH);
        float var  = sums[H2+cc]*(1.f/NBATCH) - mean*mean;
        float rstd = rsqrtf(var + EPS);
        y[c] = (hvv[c] - mean)*rstd*gamma[cc] + beta[cc];
    }
    float lg[7];
    #pragma unroll
    for (int j = 0; j < 7; ++j) {
        float p = 0.f;
        #pragma unroll
        for (int c = 0; c < 4; ++c) p += y[c]*fc2_w[(size_t)(c0+c)*7 + j];
        #pragma unroll
        for (int off = 32; off >= 1; off >>= 1) p += __shfl_xor(p, off, 64);
        lg[j] = p + fc2_b[j];
    }
    if (lane == 0) {
        float m = lg[0];
        #pragma unroll
        for (int j = 1; j < 7; ++j) m = fmaxf(m, lg[j]);
        float ev[7]; float s = 0.f;
        #pragma unroll
        for (int j = 0; j < 7; ++j) { ev[j] = expf(lg[j]-m); s += ev[j]; }
        float inv = 1.f/s;
        #pragma unroll
        for (int j = 0; j < 7; ++j) out[(size_t)r*7 + j] = ev[j]*inv;
    }
}

// ---------------------------------------------------------------------------
extern "C" void kernel_launch(void* const* d_in, const int* in_sizes, int n_in,
                              void* d_out, int out_size, void* d_ws, size_t ws_size,
                              hipStream_t stream)
{
    (void)in_sizes; (void)n_in; (void)out_size; (void)ws_size;
    const float* x     = (const float*)d_in[0];
    const float* adj   = (const float*)d_in[1];
    const float* W0    = (const float*)d_in[2];
    const float* b0    = (const float*)d_in[3];
    const float* W1    = (const float*)d_in[4];
    const float* b1    = (const float*)d_in[5];
    const float* W2    = (const float*)d_in[6];
    const float* b2    = (const float*)d_in[7];
    const float* fc1w  = (const float*)d_in[8];
    const float* fc1b  = (const float*)d_in[9];
    const float* gamma = (const float*)d_in[10];
    const float* beta  = (const float*)d_in[11];
    const float* fc2w  = (const float*)d_in[12];
    const float* fc2b  = (const float*)d_in[13];
    float* out = (float*)d_out;

    char* ws = (char*)d_ws;
    float* xs   = (float*)(ws);                                  // 8192*325 f32
    float* hbuf = (float*)(ws + 10649600);                       // 8192*256 f32
    float* sums = (float*)(ws + 10649600 + 8388608);             // 512 f32

    hipMemsetAsync(sums, 0, 512*sizeof(float), stream);
    rnn_kernel<<<NBATCH/NB, 512, 0, stream>>>(x, adj, W0, b0, W1, b1, W2, b2, xs);
    fc1_kernel<<<NBATCH/16, 256, 0, stream>>>(xs, fc1w, fc1b, hbuf, sums);
    head_kernel<<<NBATCH/4, 256, 0, stream>>>(hbuf, sums, gamma, beta, fc2w, fc2b, out);
}

// Round 4
// 3458.852 us; speedup vs baseline: 2.0935x; 1.0425x over previous
//
#include <hip/hip_runtime.h>
#include <math.h>

#define NODE 5
#define TT 512
#define NBATCH 8192
#define NB 16            // batch elems per block
#define MR (NB*NODE)     // 80 rows (row80 = node*16 + e)
#define TB 32
#define XS_DIM 325
#define H2 256
#define EPS 1e-5f

typedef _Float16 h16;
typedef __attribute__((ext_vector_type(8))) _Float16 half8;
typedef __attribute__((ext_vector_type(4))) _Float16 h16x4;
typedef __attribute__((ext_vector_type(4))) float float4v;

// XOR-swizzle on the 8-half chunk index vs row&7 — spreads the mod-32-dword
// row stride across all banks. Both-sides-or-neither: applied to every access.
__device__ __forceinline__ int swz128(int row, int hc) {   // G1/G2 (128-wide)
    return row*128 + (hc ^ ((row & 7) << 3));
}
__device__ __forceinline__ int swz64(int row, int hc) {    // GS (64-wide)
    return row*64 + (hc ^ ((row & 7) << 3));
}

// ---------------------------------------------------------------------------
// RNN kernel, 512 threads (8 waves), row80 = node*16 + e (node-major).
// Per step only 3 phases / 3 barriers:
//   L1 (all 8 waves, feat tile w): MFMA + relu + IN-REGISTER node-mix -> G1
//   L2 (all 8 waves):              MFMA + relu + in-register mix      -> G2
//   L3 (waves 0..3, 64 feats):     MFMA + tanh + in-register mix      -> GS
// The 5x5 node-mix runs on registers because all 5 node-values of a batch
// element sit in the same lane (col = ln = e) across the nd-loop accumulators.
// x-mix (sxg) precomputed per 32-step chunk. adj forced to SGPRs.
// __launch_bounds__(512,2): empirically caps VGPR at 128 (2 blocks/CU).
// ---------------------------------------------------------------------------
__global__ __launch_bounds__(512, 2) void rnn_kernel(
    const float* __restrict__ x, const float* __restrict__ adj,
    const float* __restrict__ W0, const float* __restrict__ b0,
    const float* __restrict__ W1, const float* __restrict__ b1,
    const float* __restrict__ W2, const float* __restrict__ b2,
    float* __restrict__ xs)
{
    __shared__ __align__(16) h16 sG1[MR*128];   // 20480 B  (L1 out, mixed)
    __shared__ __align__(16) h16 sG2[MR*128];   // 20480 B  (L2 out, mixed)
    __shared__ __align__(16) h16 sGS[MR*64];    // 10240 B  (L3 out, mixed state)
    __shared__ h16  sx[2][TB][NODE][16];        // 10240 B  (x chunks, dbuf)
    __shared__ float sxg[TB][MR];               // 10240 B  (mixed x, per chunk)

    const int tid  = threadIdx.x;
    const int lane = tid & 63;
    const int w    = tid >> 6;       // wave 0..7
    const int ln   = lane & 15;      // col = batch elem e
    const int q    = lane >> 4;      // quad 0..3
    const int k0q  = q*8;
    const int bbase = blockIdx.x * NB;

    // ---- A = adj.T, wave-uniform -> force into SGPRs ----
    float af[NODE][NODE];
    #pragma unroll
    for (int i = 0; i < NODE; ++i)
        #pragma unroll
        for (int j = 0; j < NODE; ++j)
            af[i][j] = __uint_as_float(
                __builtin_amdgcn_readfirstlane(__float_as_uint(adj[j*NODE + i])));

    // ---- weight fragments (VGPRs): one 16-feat tile per wave ----
    // A-frag of W^T: lane holds W[k = ks*32 + q*8 + j][feat = tile*16 + ln].
    half8 wf0[2], wf1f[4], wf3[4];
    {
        int n1 = w*16 + ln;
        #pragma unroll
        for (int ks = 0; ks < 2; ++ks) {
            half8 f;
            #pragma unroll
            for (int j = 0; j < 8; ++j)
                f[j] = (h16)W0[(size_t)(1 + ks*32 + k0q + j)*128 + n1]; // rows 1..64
            wf0[ks] = f;
        }
        #pragma unroll
        for (int ks = 0; ks < 4; ++ks) {
            half8 f;
            #pragma unroll
            for (int j = 0; j < 8; ++j)
                f[j] = (h16)W1[(size_t)(ks*32 + k0q + j)*128 + n1];
            wf1f[ks] = f;
        }
        int n3 = (w&3)*16 + ln;
        #pragma unroll
        for (int ks = 0; ks < 4; ++ks) {
            half8 f;
            #pragma unroll
            for (int j = 0; j < 8; ++j)
                f[j] = (h16)W2[(size_t)(ks*32 + k0q + j)*64 + n3];
            wf3[ks] = f;
        }
    }
    // Epilogue constants indexed by output feature (feat = tile*16 + q*4 + r).
    float b0s[4], w0s[4], b1s[4], b2s[4];
    #pragma unroll
    for (int r = 0; r < 4; ++r) {
        int fi = w*16 + q*4 + r;
        b0s[r] = b0[fi];
        w0s[r] = W0[fi];             // W0 row 0 (x rank-1 term)
        b1s[r] = b1[fi];
        b2s[r] = b2[(w&3)*16 + q*4 + r];
    }

    // ---- prologue: stage x chunk 0, zero initial mixed state ----
    for (int i = tid; i < TB*NODE*16; i += 512) {
        int tl = i & 31; int ne = i >> 5; int n = ne >> 4; int e = ne & 15;
        sx[0][tl][n][e] = (h16)x[((size_t)(bbase+e)*NODE + n)*TT + tl];
    }
    for (int i = tid; i < MR*64; i += 512) sGS[i] = (h16)0.f;
    __syncthreads();

    #pragma unroll 1
    for (int tc = 0; tc < TT/TB; ++tc) {
        const int buf = tc & 1;
        // mixed x for this chunk: sxg[ti][nd*16+e] = sum_j af[nd][j]*x[e][j][t]
        for (int i = tid; i < TB*MR; i += 512) {
            int ti = i / MR, row = i % MR;
            int nd = row >> 4, e = row & 15;
            float acc = 0.f;
            #pragma unroll
            for (int j = 0; j < NODE; ++j)
                acc += af[nd][j] * (float)sx[buf][ti][j][e];
            sxg[ti][row] = acc;
        }
        if (tc+1 < TT/TB) {   // stage next chunk (other buffer)
            for (int i = tid; i < TB*NODE*16; i += 512) {
                int tl = i & 31; int ne = i >> 5; int n = ne >> 4; int e = ne & 15;
                sx[buf^1][tl][n][e] =
                    (h16)x[((size_t)(bbase+e)*NODE + n)*TT + (tc+1)*TB + tl];
            }
        }
        __syncthreads();

        #pragma unroll 1
        for (int tt = 0; tt < TB; ++tt) {
            const int t = tc*TB + tt;
            // ---------------- L1 + mix: G1 = A @ relu([x|gS] W0) ----------
            {
                float g[NODE][4];
                #pragma unroll
                for (int i = 0; i < NODE; ++i)
                    #pragma unroll
                    for (int r = 0; r < 4; ++r) g[i][r] = 0.f;
                #pragma unroll
                for (int nd = 0; nd < NODE; ++nd) {
                    const int row = nd*16 + ln;
                    half8 a0 = *(const half8*)&sGS[swz64(row, 0  + k0q)];
                    half8 a1 = *(const half8*)&sGS[swz64(row, 32 + k0q)];
                    float4v acc = {0.f,0.f,0.f,0.f};
                    acc = __builtin_amdgcn_mfma_f32_16x16x32_f16(wf0[0], a0, acc, 0,0,0);
                    acc = __builtin_amdgcn_mfma_f32_16x16x32_f16(wf0[1], a1, acc, 0,0,0);
                    float xg = sxg[tt][row];
                    #pragma unroll
                    for (int r = 0; r < 4; ++r) {
                        float v = fmaxf(acc[r] + b0s[r] + xg*w0s[r], 0.f);
                        #pragma unroll
                        for (int i = 0; i < NODE; ++i) g[i][r] += af[i][nd]*v;
                    }
                }
                #pragma unroll
                for (int i = 0; i < NODE; ++i) {
                    h16x4 o;
                    #pragma unroll
                    for (int r = 0; r < 4; ++r) o[r] = (h16)g[i][r];
                    *(h16x4*)&sG1[swz128(i*16+ln, w*16 + q*4)] = o;
                }
            }
            __syncthreads();
            // ---------------- L2 + mix: G2 = A @ relu(G1 W1) --------------
            {
                float g[NODE][4];
                #pragma unroll
                for (int i = 0; i < NODE; ++i)
                    #pragma unroll
                    for (int r = 0; r < 4; ++r) g[i][r] = 0.f;
                #pragma unroll
                for (int nd = 0; nd < NODE; ++nd) {
                    const int row = nd*16 + ln;
                    half8 a[4];
                    #pragma unroll
                    for (int ks = 0; ks < 4; ++ks)
                        a[ks] = *(const half8*)&sG1[swz128(row, ks*32 + k0q)];
                    float4v acc = {0.f,0.f,0.f,0.f};
                    #pragma unroll
                    for (int ks = 0; ks < 4; ++ks)
                        acc = __builtin_amdgcn_mfma_f32_16x16x32_f16(wf1f[ks], a[ks], acc, 0,0,0);
                    #pragma unroll
                    for (int r = 0; r < 4; ++r) {
                        float v = fmaxf(acc[r] + b1s[r], 0.f);
                        #pragma unroll
                        for (int i = 0; i < NODE; ++i) g[i][r] += af[i][nd]*v;
                    }
                }
                #pragma unroll
                for (int i = 0; i < NODE; ++i) {
                    h16x4 o;
                    #pragma unroll
                    for (int r = 0; r < 4; ++r) o[r] = (h16)g[i][r];
                    *(h16x4*)&sG2[swz128(i*16+ln, w*16 + q*4)] = o;
                }
            }
            __syncthreads();
            // ------- L3 + mix: state = tanh(G2 W2); GS = A @ state --------
            if (w < 4) {
                float g[NODE][4];
                #pragma unroll
                for (int i = 0; i < NODE; ++i)
                    #pragma unroll
                    for (int r = 0; r < 4; ++r) g[i][r] = 0.f;
                #pragma unroll
                for (int nd = 0; nd < NODE; ++nd) {
                    const int row = nd*16 + ln;
                    half8 a[4];
                    #pragma unroll
                    for (int ks = 0; ks < 4; ++ks)
                        a[ks] = *(const half8*)&sG2[swz128(row, ks*32 + k0q)];
                    float4v acc = {0.f,0.f,0.f,0.f};
                    #pragma unroll
                    for (int ks = 0; ks < 4; ++ks)
                        acc = __builtin_amdgcn_mfma_f32_16x16x32_f16(wf3[ks], a[ks], acc, 0,0,0);
                    float th[4];
                    #pragma unroll
                    for (int r = 0; r < 4; ++r) {
                        float z = acc[r] + b2s[r];
                        float e = __expf(-2.f*fabsf(z));
                        th[r] = copysignf((1.f - e)/(1.f + e), z);
                    }
                    if (t == TT-1) {   // raw state straight to xs (once)
                        size_t ob = (size_t)(bbase+ln)*XS_DIM + 5 + nd*64 + w*16 + q*4;
                        #pragma unroll
                        for (int r = 0; r < 4; ++r) xs[ob + r] = th[r];
                    }
                    #pragma unroll
                    for (int r = 0; r < 4; ++r)
                        #pragma unroll
                        for (int i = 0; i < NODE; ++i) g[i][r] += af[i][nd]*th[r];
                }
                #pragma unroll
                for (int i = 0; i < NODE; ++i) {
                    h16x4 o;
                    #pragma unroll
                    for (int r = 0; r < 4; ++r) o[r] = (h16)g[i][r];
                    *(h16x4*)&sGS[swz64(i*16+ln, w*16 + q*4)] = o;
                }
            }
            __syncthreads();
        }
    }

    // ---- epilogue: x_end -> xs[b][0..4] ----
    if (tid < NB*NODE) {
        int e = tid / NODE, j = tid % NODE;
        xs[(size_t)(bbase+e)*XS_DIM + j] = (float)sx[1][TB-1][j][e];   // t=511
    }
}

// ---------------------------------------------------------------------------
// Kernel B: h = relu(xs @ fc1_w + fc1_b) + per-column sum/sumsq for BN.
// ---------------------------------------------------------------------------
__global__ __launch_bounds__(256) void fc1_kernel(
    const float* __restrict__ xs, const float* __restrict__ fc1_w,
    const float* __restrict__ fc1_b, float* __restrict__ h,
    float* __restrict__ sums)
{
    __shared__ float s_xs[16*XS_DIM];
    const int tid = threadIdx.x;
    const int r0 = blockIdx.x * 16;
    for (int i = tid; i < 16*XS_DIM; i += 256)
        s_xs[i] = xs[(size_t)r0*XS_DIM + i];
    __syncthreads();

    float acc[16];
    #pragma unroll
    for (int r = 0; r < 16; ++r) acc[r] = 0.f;
    for (int k = 0; k < XS_DIM; ++k) {
        float wv = fc1_w[(size_t)k*H2 + tid];
        #pragma unroll
        for (int r = 0; r < 16; ++r) acc[r] += s_xs[r*XS_DIM + k]*wv;
    }
    float bb = fc1_b[tid];
    float ls = 0.f, lq = 0.f;
    #pragma unroll
    for (int r = 0; r < 16; ++r) {
        float v = fmaxf(acc[r] + bb, 0.f);
        h[(size_t)(r0+r)*H2 + tid] = v;
        ls += v; lq += v*v;
    }
    atomicAdd(&sums[tid], ls);
    atomicAdd(&sums[H2 + tid], lq);
}

// ---------------------------------------------------------------------------
// Kernel C: BN(train) normalize + fc2 + softmax. One wave per row.
// ---------------------------------------------------------------------------
__global__ __launch_bounds__(256) void head_kernel(
    const float* __restrict__ h, const float* __restrict__ sums,
    const float* __restrict__ gamma, const float* __restrict__ beta,
    const float* __restrict__ fc2_w, const float* __restrict__ fc2_b,
    float* __restrict__ out)
{
    const int lane = threadIdx.x & 63;
    const int r = blockIdx.x*4 + (threadIdx.x >> 6);
    const int c0 = lane*4;

    float4 hv = *(const float4*)&h[(size_t)r*H2 + c0];
    float hvv[4] = {hv.x, hv.y, hv.z, hv.w};
    float y[4];
    #pragma unroll
    for (int c = 0; c < 4; ++c) {
        int cc = c0 + c;
        float mean = sums[cc] * (1.f/NBATCH);
        float var  = sums[H2+cc]*(1.f/NBATCH) - mean*mean;
        float rstd = rsqrtf(var + EPS);
        y[c] = (hvv[c] - mean)*rstd*gamma[cc] + beta[cc];
    }
    float lg[7];
    #pragma unroll
    for (int j = 0; j < 7; ++j) {
        float p = 0.f;
        #pragma unroll
        for (int c = 0; c < 4; ++c) p += y[c]*fc2_w[(size_t)(c0+c)*7 + j];
        #pragma unroll
        for (int off = 32; off >= 1; off >>= 1) p += __shfl_xor(p, off, 64);
        lg[j] = p + fc2_b[j];
    }
    if (lane == 0) {
        float m = lg[0];
        #pragma unroll
        for (int j = 1; j < 7; ++j) m = fmaxf(m, lg[j]);
        float ev[7]; float s = 0.f;
        #pragma unroll
        for (int j = 0; j < 7; ++j) { ev[j] = expf(lg[j]-m); s += ev[j]; }
        float inv = 1.f/s;
        #pragma unroll
        for (int j = 0; j < 7; ++j) out[(size_t)r*7 + j] = ev[j]*inv;
    }
}

// ---------------------------------------------------------------------------
extern "C" void kernel_launch(void* const* d_in, const int* in_sizes, int n_in,
                              void* d_out, int out_size, void* d_ws, size_t ws_size,
                              hipStream_t stream)
{
    (void)in_sizes; (void)n_in; (void)out_size; (void)ws_size;
    const float* x     = (const float*)d_in[0];
    const float* adj   = (const float*)d_in[1];
    const float* W0    = (const float*)d_in[2];
    const float* b0    = (const float*)d_in[3];
    const float* W1    = (const float*)d_in[4];
    const float* b1    = (const float*)d_in[5];
    const float* W2    = (const float*)d_in[6];
    const float* b2    = (const float*)d_in[7];
    const float* fc1w  = (const float*)d_in[8];
    const float* fc1b  = (const float*)d_in[9];
    const float* gamma = (const float*)d_in[10];
    const float* beta  = (const float*)d_in[11];
    const float* fc2w  = (const float*)d_in[12];
    const float* fc2b  = (const float*)d_in[13];
    float* out = (float*)d_out;

    char* ws = (char*)d_ws;
    float* xs   = (float*)(ws);                                  // 8192*325 f32
    float* hbuf = (float*)(ws + 10649600);                       // 8192*256 f32
    float* sums = (float*)(ws + 10649600 + 8388608);             // 512 f32

    hipMemsetAsync(sums, 0, 512*sizeof(float), stream);
    rnn_kernel<<<NBATCH/NB, 512, 0, stream>>>(x, adj, W0, b0, W1, b1, W2, b2, xs);
    fc1_kernel<<<NBATCH/16, 256, 0, stream>>>(xs, fc1w, fc1b, hbuf, sums);
    head_kernel<<<NBATCH/4, 256, 0, stream>>>(hbuf, sums, gamma, beta, fc2w, fc2b, out);
}

// Round 5
// 2844.809 us; speedup vs baseline: 2.5454x; 1.2158x over previous
//
#include <hip/hip_runtime.h>
#include <math.h>

#define NODE 5
#define TT 512
#define NBATCH 8192
#define NB 16            // batch elems per block
#define MR (NB*NODE)     // 80 rows (row80 = node*16 + e)
#define TB 32
#define XS_DIM 325
#define H2 256
#define EPS 1e-5f

typedef _Float16 h16;
typedef __attribute__((ext_vector_type(8))) _Float16 half8;
typedef __attribute__((ext_vector_type(4))) _Float16 h16x4;
typedef __attribute__((ext_vector_type(2))) _Float16 half2v;
typedef __attribute__((ext_vector_type(4))) float float4v;

// XOR-swizzle on the 8-half (16B) granule index vs row&7 — spreads the
// mod-32-dword row stride across banks. Bijective; preserves alignment of all
// used widths (b128 granule-contained, b64 at offsets 0/4 within granule).
// Applied to EVERY sG1/sG2/sGS access (both-sides-or-neither).
__device__ __forceinline__ int swz128(int row, int hc) {   // G1/G2 (128-wide)
    return row*128 + (hc ^ ((row & 7) << 3));
}
__device__ __forceinline__ int swz64(int row, int hc) {    // GS (64-wide)
    return row*64 + (hc ^ ((row & 7) << 3));
}

__device__ __forceinline__ float rfl_f(float v) {
    return __uint_as_float(__builtin_amdgcn_readfirstlane(__float_as_uint(v)));
}

// ---------------------------------------------------------------------------
// RNN kernel, 256 threads (4 waves), row80 = node*16 + e (node-major).
// Fused-mix structure: 3 phases / 3 barriers per step (vs 6 in the M-pass
// version). Each wave owns TWO 16-feat tiles for L1/L2 (feats w*32..w*32+31)
// and ONE for L3 — weights live in VGPRs (64 regs). The 5x5 node-mix happens
// in registers right after each MFMA epilogue (col = lane ln = batch elem, so
// the 5 node values sit in the same lane across the nd loop):
//   L1/L2 mix: packed f16 (v_pk_fma_f16) — same math as round-1's M1/M2.
//   L3  mix:   f32 (state path) — same as every passing round.
// 4 waves (not 8): per-wave B-operand reads cover the FULL input buffer, so
// total LDS traffic scales with wave count; 4-wave halves it vs round 4 and
// doubles per-wave MFMA chains (better latency hiding). 2 blocks/CU.
// __launch_bounds__(256,2) => 128-VGPR cap (empirical, rounds 0-1).
// ---------------------------------------------------------------------------
__global__ __launch_bounds__(256, 2) void rnn_kernel(
    const float* __restrict__ x, const float* __restrict__ adj,
    const float* __restrict__ W0, const float* __restrict__ b0,
    const float* __restrict__ W1, const float* __restrict__ b1,
    const float* __restrict__ W2, const float* __restrict__ b2,
    float* __restrict__ xs)
{
    __shared__ __align__(16) h16 sG1[MR*128];   // 20480 B (L1 out, mixed)
    __shared__ __align__(16) h16 sG2[MR*128];   // 20480 B (L2 out, mixed)
    __shared__ __align__(16) h16 sGS[MR*64];    // 10240 B (state, mixed)
    __shared__ h16  sx[2][TB][NODE][16];        // 10240 B (x chunks, dbuf)
    __shared__ float sxg[TB][MR];               // 10240 B (mixed x, per chunk)

    const int tid  = threadIdx.x;
    const int lane = tid & 63;
    const int w    = tid >> 6;       // wave 0..3
    const int ln   = lane & 15;      // col = batch elem e
    const int q    = lane >> 4;      // quad 0..3
    const int k0q  = q*8;
    const int bbase = blockIdx.x * NB;

    // ---- A = adj.T, wave-uniform -> SGPRs (f32 for L3/sxg, packed f16 for
    //      the L1/L2 pk mixes) ----
    float  af[NODE][NODE];
    half2v ahp[NODE][NODE];
    #pragma unroll
    for (int i = 0; i < NODE; ++i)
        #pragma unroll
        for (int j = 0; j < NODE; ++j) {
            float v = rfl_f(adj[j*NODE + i]);
            af[i][j] = v;
            h16 hv = (h16)v;
            half2v t; t[0] = hv; t[1] = hv;
            ahp[i][j] = t;
        }

    // ---- weight fragments (VGPRs): two 16-feat tiles per wave (L1/L2),
    //      one (L3). A-frag of W^T: lane holds W[ks*32+q*8+j][feat tile]. ----
    half8 wf0[2][2], wf1f[2][4], wf3[4];
    {
        #pragma unroll
        for (int t2 = 0; t2 < 2; ++t2) {
            int n1 = (2*w+t2)*16 + ln;
            #pragma unroll
            for (int ks = 0; ks < 2; ++ks) {
                half8 f;
                #pragma unroll
                for (int j = 0; j < 8; ++j)
                    f[j] = (h16)W0[(size_t)(1 + ks*32 + k0q + j)*128 + n1]; // rows 1..64
                wf0[t2][ks] = f;
            }
            #pragma unroll
            for (int ks = 0; ks < 4; ++ks) {
                half8 f;
                #pragma unroll
                for (int j = 0; j < 8; ++j)
                    f[j] = (h16)W1[(size_t)(ks*32 + k0q + j)*128 + n1];
                wf1f[t2][ks] = f;
            }
        }
        int n3 = w*16 + ln;
        #pragma unroll
        for (int ks = 0; ks < 4; ++ks) {
            half8 f;
            #pragma unroll
            for (int j = 0; j < 8; ++j)
                f[j] = (h16)W2[(size_t)(ks*32 + k0q + j)*64 + n3];
            wf3[ks] = f;
        }
    }
    // Epilogue constants indexed by output feature (feat = tile*16 + q*4 + r).
    float b0s[2][4], w0s[2][4], b1s[2][4], b2s[4];
    #pragma unroll
    for (int t2 = 0; t2 < 2; ++t2)
        #pragma unroll
        for (int r = 0; r < 4; ++r) {
            int fi = (2*w+t2)*16 + q*4 + r;
            b0s[t2][r] = b0[fi];
            w0s[t2][r] = W0[fi];         // W0 row 0 (x rank-1 term)
            b1s[t2][r] = b1[fi];
        }
    #pragma unroll
    for (int r = 0; r < 4; ++r) b2s[r] = b2[w*16 + q*4 + r];

    // ---- prologue: stage x chunk 0, zero initial mixed state ----
    for (int i = tid; i < TB*NODE*16; i += 256) {
        int tl = i & 31; int ne = i >> 5; int n = ne >> 4; int e = ne & 15;
        sx[0][tl][n][e] = (h16)x[((size_t)(bbase+e)*NODE + n)*TT + tl];
    }
    for (int i = tid; i < MR*64; i += 256) sGS[i] = (h16)0.f;
    __syncthreads();

    #pragma unroll 1
    for (int tc = 0; tc < TT/TB; ++tc) {
        const int buf = tc & 1;
        // mixed x for this chunk: sxg[ti][nd*16+e] = sum_j af[nd][j]*x[e][j][t]
        for (int i = tid; i < TB*MR; i += 256) {
            int ti = i / MR, row = i - ti*MR;
            int nd = row >> 4, e = row & 15;
            float acc = 0.f;
            #pragma unroll
            for (int j = 0; j < NODE; ++j)
                acc += af[nd][j] * (float)sx[buf][ti][j][e];
            sxg[ti][row] = acc;
        }
        if (tc+1 < TT/TB) {   // stage next chunk (other buffer)
            for (int i = tid; i < TB*NODE*16; i += 256) {
                int tl = i & 31; int ne = i >> 5; int n = ne >> 4; int e = ne & 15;
                sx[buf^1][tl][n][e] =
                    (h16)x[((size_t)(bbase+e)*NODE + n)*TT + (tc+1)*TB + tl];
            }
        }
        __syncthreads();

        #pragma unroll 1
        for (int tt = 0; tt < TB; ++tt) {
            const int t = tc*TB + tt;
            // -------- L1 + mix: G1 = A @ relu([x|gS] W0 + b0) -------------
            {
                half2v g[2][NODE][2];
                #pragma unroll
                for (int t2 = 0; t2 < 2; ++t2)
                    #pragma unroll
                    for (int i = 0; i < NODE; ++i) {
                        half2v z; z[0] = (h16)0.f; z[1] = (h16)0.f;
                        g[t2][i][0] = z; g[t2][i][1] = z;
                    }
                #pragma unroll
                for (int nd = 0; nd < NODE; ++nd) {
                    const int row = nd*16 + ln;
                    half8 a0 = *(const half8*)&sGS[swz64(row, 0  + k0q)];
                    half8 a1 = *(const half8*)&sGS[swz64(row, 32 + k0q)];
                    float xg = sxg[tt][row];
                    #pragma unroll
                    for (int t2 = 0; t2 < 2; ++t2) {
                        float4v acc = {0.f,0.f,0.f,0.f};
                        acc = __builtin_amdgcn_mfma_f32_16x16x32_f16(wf0[t2][0], a0, acc, 0,0,0);
                        acc = __builtin_amdgcn_mfma_f32_16x16x32_f16(wf0[t2][1], a1, acc, 0,0,0);
                        float v0 = fmaxf(acc[0] + b0s[t2][0] + xg*w0s[t2][0], 0.f);
                        float v1 = fmaxf(acc[1] + b0s[t2][1] + xg*w0s[t2][1], 0.f);
                        float v2 = fmaxf(acc[2] + b0s[t2][2] + xg*w0s[t2][2], 0.f);
                        float v3 = fmaxf(acc[3] + b0s[t2][3] + xg*w0s[t2][3], 0.f);
                        half2v p0; p0[0] = (h16)v0; p0[1] = (h16)v1;
                        half2v p1; p1[0] = (h16)v2; p1[1] = (h16)v3;
                        #pragma unroll
                        for (int i = 0; i < NODE; ++i) {
                            g[t2][i][0] += ahp[i][nd]*p0;
                            g[t2][i][1] += ahp[i][nd]*p1;
                        }
                    }
                }
                #pragma unroll
                for (int t2 = 0; t2 < 2; ++t2)
                    #pragma unroll
                    for (int i = 0; i < NODE; ++i) {
                        h16x4 o;
                        o[0]=g[t2][i][0][0]; o[1]=g[t2][i][0][1];
                        o[2]=g[t2][i][1][0]; o[3]=g[t2][i][1][1];
                        *(h16x4*)&sG1[swz128(i*16+ln, (2*w+t2)*16 + q*4)] = o;
                    }
            }
            __syncthreads();
            // -------- L2 + mix: G2 = A @ relu(G1 W1 + b1) -----------------
            {
                half2v g[2][NODE][2];
                #pragma unroll
                for (int t2 = 0; t2 < 2; ++t2)
                    #pragma unroll
                    for (int i = 0; i < NODE; ++i) {
                        half2v z; z[0] = (h16)0.f; z[1] = (h16)0.f;
                        g[t2][i][0] = z; g[t2][i][1] = z;
                    }
                #pragma unroll
                for (int nd = 0; nd < NODE; ++nd) {
                    const int row = nd*16 + ln;
                    half8 a[4];
                    #pragma unroll
                    for (int ks = 0; ks < 4; ++ks)
                        a[ks] = *(const half8*)&sG1[swz128(row, ks*32 + k0q)];
                    #pragma unroll
                    for (int t2 = 0; t2 < 2; ++t2) {
                        float4v acc = {0.f,0.f,0.f,0.f};
                        #pragma unroll
                        for (int ks = 0; ks < 4; ++ks)
                            acc = __builtin_amdgcn_mfma_f32_16x16x32_f16(wf1f[t2][ks], a[ks], acc, 0,0,0);
                        float v0 = fmaxf(acc[0] + b1s[t2][0], 0.f);
                        float v1 = fmaxf(acc[1] + b1s[t2][1], 0.f);
                        float v2 = fmaxf(acc[2] + b1s[t2][2], 0.f);
                        float v3 = fmaxf(acc[3] + b1s[t2][3], 0.f);
                        half2v p0; p0[0] = (h16)v0; p0[1] = (h16)v1;
                        half2v p1; p1[0] = (h16)v2; p1[1] = (h16)v3;
                        #pragma unroll
                        for (int i = 0; i < NODE; ++i) {
                            g[t2][i][0] += ahp[i][nd]*p0;
                            g[t2][i][1] += ahp[i][nd]*p1;
                        }
                    }
                }
                #pragma unroll
                for (int t2 = 0; t2 < 2; ++t2)
                    #pragma unroll
                    for (int i = 0; i < NODE; ++i) {
                        h16x4 o;
                        o[0]=g[t2][i][0][0]; o[1]=g[t2][i][0][1];
                        o[2]=g[t2][i][1][0]; o[3]=g[t2][i][1][1];
                        *(h16x4*)&sG2[swz128(i*16+ln, (2*w+t2)*16 + q*4)] = o;
                    }
            }
            __syncthreads();
            // -------- L3 + mix: state = tanh(G2 W2 + b2); GS = A @ state --
            {
                float gs[NODE][4];
                #pragma unroll
                for (int i = 0; i < NODE; ++i)
                    #pragma unroll
                    for (int r = 0; r < 4; ++r) gs[i][r] = 0.f;
                #pragma unroll
                for (int nd = 0; nd < NODE; ++nd) {
                    const int row = nd*16 + ln;
                    half8 a[4];
                    #pragma unroll
                    for (int ks = 0; ks < 4; ++ks)
                        a[ks] = *(const half8*)&sG2[swz128(row, ks*32 + k0q)];
                    float4v acc = {0.f,0.f,0.f,0.f};
                    #pragma unroll
                    for (int ks = 0; ks < 4; ++ks)
                        acc = __builtin_amdgcn_mfma_f32_16x16x32_f16(wf3[ks], a[ks], acc, 0,0,0);
                    float th[4];
                    #pragma unroll
                    for (int r = 0; r < 4; ++r) {
                        float z = acc[r] + b2s[r];
                        float e = __expf(-2.f*fabsf(z));
                        th[r] = copysignf((1.f - e)/(1.f + e), z);
                    }
                    if (t == TT-1) {   // raw state straight to xs (once)
                        size_t ob = (size_t)(bbase+ln)*XS_DIM + 5 + nd*64 + w*16 + q*4;
                        #pragma unroll
                        for (int r = 0; r < 4; ++r) xs[ob + r] = th[r];
                    }
                    #pragma unroll
                    for (int r = 0; r < 4; ++r)
                        #pragma unroll
                        for (int i = 0; i < NODE; ++i) gs[i][r] += af[i][nd]*th[r];
                }
                #pragma unroll
                for (int i = 0; i < NODE; ++i) {
                    h16x4 o;
                    #pragma unroll
                    for (int r = 0; r < 4; ++r) o[r] = (h16)gs[i][r];
                    *(h16x4*)&sGS[swz64(i*16+ln, w*16 + q*4)] = o;
                }
            }
            __syncthreads();
        }
    }

    // ---- epilogue: x_end -> xs[b][0..4] ----
    if (tid < NB*NODE) {
        int e = tid / NODE, j = tid - (tid/NODE)*NODE;
        xs[(size_t)(bbase+e)*XS_DIM + j] = (float)sx[1][TB-1][j][e];   // t=511
    }
}

// ---------------------------------------------------------------------------
// Kernel B: h = relu(xs @ fc1_w + fc1_b) + per-column sum/sumsq for BN.
// ---------------------------------------------------------------------------
__global__ __launch_bounds__(256) void fc1_kernel(
    const float* __restrict__ xs, const float* __restrict__ fc1_w,
    const float* __restrict__ fc1_b, float* __restrict__ h,
    float* __restrict__ sums)
{
    __shared__ float s_xs[16*XS_DIM];
    const int tid = threadIdx.x;
    const int r0 = blockIdx.x * 16;
    for (int i = tid; i < 16*XS_DIM; i += 256)
        s_xs[i] = xs[(size_t)r0*XS_DIM + i];
    __syncthreads();

    float acc[16];
    #pragma unroll
    for (int r = 0; r < 16; ++r) acc[r] = 0.f;
    for (int k = 0; k < XS_DIM; ++k) {
        float wv = fc1_w[(size_t)k*H2 + tid];
        #pragma unroll
        for (int r = 0; r < 16; ++r) acc[r] += s_xs[r*XS_DIM + k]*wv;
    }
    float bb = fc1_b[tid];
    float ls = 0.f, lq = 0.f;
    #pragma unroll
    for (int r = 0; r < 16; ++r) {
        float v = fmaxf(acc[r] + bb, 0.f);
        h[(size_t)(r0+r)*H2 + tid] = v;
        ls += v; lq += v*v;
    }
    atomicAdd(&sums[tid], ls);
    atomicAdd(&sums[H2 + tid], lq);
}

// ---------------------------------------------------------------------------
// Kernel C: BN(train) normalize + fc2 + softmax. One wave per row.
// ---------------------------------------------------------------------------
__global__ __launch_bounds__(256) void head_kernel(
    const float* __restrict__ h, const float* __restrict__ sums,
    const float* __restrict__ gamma, const float* __restrict__ beta,
    const float* __restrict__ fc2_w, const float* __restrict__ fc2_b,
    float* __restrict__ out)
{
    const int lane = threadIdx.x & 63;
    const int r = blockIdx.x*4 + (threadIdx.x >> 6);
    const int c0 = lane*4;

    float4 hv = *(const float4*)&h[(size_t)r*H2 + c0];
    float hvv[4] = {hv.x, hv.y, hv.z, hv.w};
    float y[4];
    #pragma unroll
    for (int c = 0; c < 4; ++c) {
        int cc = c0 + c;
        float mean = sums[cc] * (1.f/NBATCH);
        float var  = sums[H2+cc]*(1.f/NBATCH) - mean*mean;
        float rstd = rsqrtf(var + EPS);
        y[c] = (hvv[c] - mean)*rstd*gamma[cc] + beta[cc];
    }
    float lg[7];
    #pragma unroll
    for (int j = 0; j < 7; ++j) {
        float p = 0.f;
        #pragma unroll
        for (int c = 0; c < 4; ++c) p += y[c]*fc2_w[(size_t)(c0+c)*7 + j];
        #pragma unroll
        for (int off = 32; off >= 1; off >>= 1) p += __shfl_xor(p, off, 64);
        lg[j] = p + fc2_b[j];
    }
    if (lane == 0) {
        float m = lg[0];
        #pragma unroll
        for (int j = 1; j < 7; ++j) m = fmaxf(m, lg[j]);
        float ev[7]; float s = 0.f;
        #pragma unroll
        for (int j = 0; j < 7; ++j) { ev[j] = expf(lg[j]-m); s += ev[j]; }
        float inv = 1.f/s;
        #pragma unroll
        for (int j = 0; j < 7; ++j) out[(size_t)r*7 + j] = ev[j]*inv;
    }
}

// ---------------------------------------------------------------------------
extern "C" void kernel_launch(void* const* d_in, const int* in_sizes, int n_in,
                              void* d_out, int out_size, void* d_ws, size_t ws_size,
                              hipStream_t stream)
{
    (void)in_sizes; (void)n_in; (void)out_size; (void)ws_size;
    const float* x     = (const float*)d_in[0];
    const float* adj   = (const float*)d_in[1];
    const float* W0    = (const float*)d_in[2];
    const float* b0    = (const float*)d_in[3];
    const float* W1    = (const float*)d_in[4];
    const float* b1    = (const float*)d_in[5];
    const float* W2    = (const float*)d_in[6];
    const float* b2    = (const float*)d_in[7];
    const float* fc1w  = (const float*)d_in[8];
    const float* fc1b  = (const float*)d_in[9];
    const float* gamma = (const float*)d_in[10];
    const float* beta  = (const float*)d_in[11];
    const float* fc2w  = (const float*)d_in[12];
    const float* fc2b  = (const float*)d_in[13];
    float* out = (float*)d_out;

    char* ws = (char*)d_ws;
    float* xs   = (float*)(ws);                                  // 8192*325 f32
    float* hbuf = (float*)(ws + 10649600);                       // 8192*256 f32
    float* sums = (float*)(ws + 10649600 + 8388608);             // 512 f32

    hipMemsetAsync(sums, 0, 512*sizeof(float), stream);
    rnn_kernel<<<NBATCH/NB, 256, 0, stream>>>(x, adj, W0, b0, W1, b1, W2, b2, xs);
    fc1_kernel<<<NBATCH/16, 256, 0, stream>>>(xs, fc1w, fc1b, hbuf, sums);
    head_kernel<<<NBATCH/4, 256, 0, stream>>>(hbuf, sums, gamma, beta, fc2w, fc2b, out);
}

// Round 6
// 2695.348 us; speedup vs baseline: 2.6865x; 1.0555x over previous
//
#include <hip/hip_runtime.h>
#include <math.h>

#define NODE 5
#define TT 512
#define NBATCH 8192
#define NB 16            // batch elems per block
#define MR (NB*NODE)     // 80 rows (row80 = node*16 + e)
#define TB 32
#define XS_DIM 325
#define H2 256
#define EPS 1e-5f

typedef _Float16 h16;
typedef __attribute__((ext_vector_type(8))) _Float16 half8;
typedef __attribute__((ext_vector_type(4))) _Float16 h16x4;
typedef __attribute__((ext_vector_type(2))) _Float16 half2v;
typedef __attribute__((ext_vector_type(4))) float float4v;
typedef __attribute__((ext_vector_type(2))) __fp16 fp16x2b;

// XOR-swizzle on the 8-half (16B) granule index vs row&7 — spreads the
// mod-32-dword row stride across banks. Bijective; preserves alignment of all
// used widths. Applied to EVERY sGD/sGS access (both-sides-or-neither).
__device__ __forceinline__ int swz128(int row, int hc) {   // GD (128-wide)
    return row*128 + (hc ^ ((row & 7) << 3));
}
__device__ __forceinline__ int swz64(int row, int hc) {    // GS (64-wide)
    return row*64 + (hc ^ ((row & 7) << 3));
}

__device__ __forceinline__ float rfl_f(float v) {
    return __uint_as_float(__builtin_amdgcn_readfirstlane(__float_as_uint(v)));
}
// v_cvt_pkrtz_f16_f32: 1 instr packs 2 f32 -> 2 f16 (RTZ; mix inputs only).
__device__ __forceinline__ half2v pkrtz(float a, float b) {
    return __builtin_bit_cast(half2v, __builtin_amdgcn_cvt_pkrtz(a, b));
}
__device__ __forceinline__ half2v pkmax0(half2v v) {
    half2v z; z[0] = (h16)0.f; z[1] = (h16)0.f;
    return __builtin_elementwise_max(v, z);
}

// ---------------------------------------------------------------------------
// RNN kernel, 256 threads (4 waves), row80 = node*16 + e (node-major),
// fused-mix structure (3 barriers/step). Round-6 deltas (VALU-cut only,
// structure frozen from round 5):
//  - bias enters as the MFMA C-operand of the first chain link (no v_adds)
//  - L2 epilogue: cvt_pkrtz + v_pk_max_f16 (packed relu)
//  - L1 epilogue: f32 xg-fma + relu (accuracy), then pkrtz for the mix
//  - sG1/sG2 merged into sGD[2] so L3/L2 share L2/L1 addressing (+20480 imm)
// State path (L3 tanh, f32 mix, RTE cast to GS) unchanged from passing rounds.
// __launch_bounds__(256,2) => 128-VGPR cap (empirical: rounds 0-1, 5).
// ---------------------------------------------------------------------------
__global__ __launch_bounds__(256, 2) void rnn_kernel(
    const float* __restrict__ x, const float* __restrict__ adj,
    const float* __restrict__ W0, const float* __restrict__ b0,
    const float* __restrict__ W1, const float* __restrict__ b1,
    const float* __restrict__ W2, const float* __restrict__ b2,
    float* __restrict__ xs)
{
    __shared__ __align__(16) h16 sGD[2][MR*128]; // 40960 B (L1 out / L2 out)
    __shared__ __align__(16) h16 sGS[MR*64];     // 10240 B (state, mixed)
    __shared__ h16  sx[2][TB][NODE][16];         // 10240 B (x chunks, dbuf)
    __shared__ float sxg[TB][MR];                // 10240 B (mixed x, per chunk)

    const int tid  = threadIdx.x;
    const int lane = tid & 63;
    const int w    = tid >> 6;       // wave 0..3
    const int ln   = lane & 15;      // col = batch elem e
    const int q    = lane >> 4;      // quad 0..3
    const int k0q  = q*8;
    const int bbase = blockIdx.x * NB;

    // ---- A = adj.T, wave-uniform -> SGPRs (f32 for L3/sxg, packed f16 for
    //      the L1/L2 pk mixes) ----
    float  af[NODE][NODE];
    half2v ahp[NODE][NODE];
    #pragma unroll
    for (int i = 0; i < NODE; ++i)
        #pragma unroll
        for (int j = 0; j < NODE; ++j) {
            float v = rfl_f(adj[j*NODE + i]);
            af[i][j] = v;
            h16 hv = (h16)v;
            half2v t; t[0] = hv; t[1] = hv;
            ahp[i][j] = t;
        }

    // ---- weight fragments (VGPRs): two 16-feat tiles per wave (L1/L2),
    //      one (L3). A-frag of W^T: lane holds W[ks*32+q*8+j][feat tile]. ----
    half8 wf0[2][2], wf1f[2][4], wf3[4];
    {
        #pragma unroll
        for (int t2 = 0; t2 < 2; ++t2) {
            int n1 = (2*w+t2)*16 + ln;
            #pragma unroll
            for (int ks = 0; ks < 2; ++ks) {
                half8 f;
                #pragma unroll
                for (int j = 0; j < 8; ++j)
                    f[j] = (h16)W0[(size_t)(1 + ks*32 + k0q + j)*128 + n1]; // rows 1..64
                wf0[t2][ks] = f;
            }
            #pragma unroll
            for (int ks = 0; ks < 4; ++ks) {
                half8 f;
                #pragma unroll
                for (int j = 0; j < 8; ++j)
                    f[j] = (h16)W1[(size_t)(ks*32 + k0q + j)*128 + n1];
                wf1f[t2][ks] = f;
            }
        }
        int n3 = w*16 + ln;
        #pragma unroll
        for (int ks = 0; ks < 4; ++ks) {
            half8 f;
            #pragma unroll
            for (int j = 0; j < 8; ++j)
                f[j] = (h16)W2[(size_t)(ks*32 + k0q + j)*64 + n3];
            wf3[ks] = f;
        }
    }
    // Bias quads (MFMA C-operand init) + W0 row-0 (x rank-1), per out-feature
    // (feat = tile*16 + q*4 + r).
    float4v b0q[2], b1q[2], b2q;
    float w0s[2][4];
    #pragma unroll
    for (int t2 = 0; t2 < 2; ++t2)
        #pragma unroll
        for (int r = 0; r < 4; ++r) {
            int fi = (2*w+t2)*16 + q*4 + r;
            b0q[t2][r] = b0[fi];
            w0s[t2][r] = W0[fi];
            b1q[t2][r] = b1[fi];
        }
    #pragma unroll
    for (int r = 0; r < 4; ++r) b2q[r] = b2[w*16 + q*4 + r];

    // ---- prologue: stage x chunk 0, zero initial mixed state ----
    for (int i = tid; i < TB*NODE*16; i += 256) {
        int tl = i & 31; int ne = i >> 5; int n = ne >> 4; int e = ne & 15;
        sx[0][tl][n][e] = (h16)x[((size_t)(bbase+e)*NODE + n)*TT + tl];
    }
    for (int i = tid; i < MR*64; i += 256) sGS[i] = (h16)0.f;
    __syncthreads();

    #pragma unroll 1
    for (int tc = 0; tc < TT/TB; ++tc) {
        const int buf = tc & 1;
        // mixed x for this chunk: sxg[ti][nd*16+e] = sum_j af[nd][j]*x[e][j][t]
        for (int i = tid; i < TB*MR; i += 256) {
            int ti = i / MR, row = i - ti*MR;
            int nd = row >> 4, e = row & 15;
            float acc = 0.f;
            #pragma unroll
            for (int j = 0; j < NODE; ++j)
                acc += af[nd][j] * (float)sx[buf][ti][j][e];
            sxg[ti][row] = acc;
        }
        if (tc+1 < TT/TB) {   // stage next chunk (other buffer)
            for (int i = tid; i < TB*NODE*16; i += 256) {
                int tl = i & 31; int ne = i >> 5; int n = ne >> 4; int e = ne & 15;
                sx[buf^1][tl][n][e] =
                    (h16)x[((size_t)(bbase+e)*NODE + n)*TT + (tc+1)*TB + tl];
            }
        }
        __syncthreads();

        #pragma unroll 1
        for (int tt = 0; tt < TB; ++tt) {
            const int t = tc*TB + tt;
            // -------- L1 + mix: G1 = A @ relu([x|gS] W0 + b0) -------------
            {
                half2v g[2][NODE][2];
                #pragma unroll
                for (int t2 = 0; t2 < 2; ++t2)
                    #pragma unroll
                    for (int i = 0; i < NODE; ++i) {
                        half2v z; z[0] = (h16)0.f; z[1] = (h16)0.f;
                        g[t2][i][0] = z; g[t2][i][1] = z;
                    }
                #pragma unroll
                for (int nd = 0; nd < NODE; ++nd) {
                    const int row = nd*16 + ln;
                    half8 a0 = *(const half8*)&sGS[swz64(row, 0  + k0q)];
                    half8 a1 = *(const half8*)&sGS[swz64(row, 32 + k0q)];
                    float xg = sxg[tt][row];
                    #pragma unroll
                    for (int t2 = 0; t2 < 2; ++t2) {
                        float4v acc = __builtin_amdgcn_mfma_f32_16x16x32_f16(wf0[t2][0], a0, b0q[t2], 0,0,0);
                        acc = __builtin_amdgcn_mfma_f32_16x16x32_f16(wf0[t2][1], a1, acc, 0,0,0);
                        float v0 = fmaxf(acc[0] + xg*w0s[t2][0], 0.f);
                        float v1 = fmaxf(acc[1] + xg*w0s[t2][1], 0.f);
                        float v2 = fmaxf(acc[2] + xg*w0s[t2][2], 0.f);
                        float v3 = fmaxf(acc[3] + xg*w0s[t2][3], 0.f);
                        half2v p0 = pkrtz(v0, v1);
                        half2v p1 = pkrtz(v2, v3);
                        #pragma unroll
                        for (int i = 0; i < NODE; ++i) {
                            g[t2][i][0] += ahp[i][nd]*p0;
                            g[t2][i][1] += ahp[i][nd]*p1;
                        }
                    }
                }
                #pragma unroll
                for (int t2 = 0; t2 < 2; ++t2)
                    #pragma unroll
                    for (int i = 0; i < NODE; ++i) {
                        h16x4 o;
                        o[0]=g[t2][i][0][0]; o[1]=g[t2][i][0][1];
                        o[2]=g[t2][i][1][0]; o[3]=g[t2][i][1][1];
                        *(h16x4*)&sGD[0][swz128(i*16+ln, (2*w+t2)*16 + q*4)] = o;
                    }
            }
            __syncthreads();
            // -------- L2 + mix: G2 = A @ relu(G1 W1 + b1) -----------------
            {
                half2v g[2][NODE][2];
                #pragma unroll
                for (int t2 = 0; t2 < 2; ++t2)
                    #pragma unroll
                    for (int i = 0; i < NODE; ++i) {
                        half2v z; z[0] = (h16)0.f; z[1] = (h16)0.f;
                        g[t2][i][0] = z; g[t2][i][1] = z;
                    }
                #pragma unroll
                for (int nd = 0; nd < NODE; ++nd) {
                    const int row = nd*16 + ln;
                    half8 a[4];
                    #pragma unroll
                    for (int ks = 0; ks < 4; ++ks)
                        a[ks] = *(const half8*)&sGD[0][swz128(row, ks*32 + k0q)];
                    #pragma unroll
                    for (int t2 = 0; t2 < 2; ++t2) {
                        float4v acc = __builtin_amdgcn_mfma_f32_16x16x32_f16(wf1f[t2][0], a[0], b1q[t2], 0,0,0);
                        #pragma unroll
                        for (int ks = 1; ks < 4; ++ks)
                            acc = __builtin_amdgcn_mfma_f32_16x16x32_f16(wf1f[t2][ks], a[ks], acc, 0,0,0);
                        half2v p0 = pkmax0(pkrtz(acc[0], acc[1]));
                        half2v p1 = pkmax0(pkrtz(acc[2], acc[3]));
                        #pragma unroll
                        for (int i = 0; i < NODE; ++i) {
                            g[t2][i][0] += ahp[i][nd]*p0;
                            g[t2][i][1] += ahp[i][nd]*p1;
                        }
                    }
                }
                #pragma unroll
                for (int t2 = 0; t2 < 2; ++t2)
                    #pragma unroll
                    for (int i = 0; i < NODE; ++i) {
                        h16x4 o;
                        o[0]=g[t2][i][0][0]; o[1]=g[t2][i][0][1];
                        o[2]=g[t2][i][1][0]; o[3]=g[t2][i][1][1];
                        *(h16x4*)&sGD[1][swz128(i*16+ln, (2*w+t2)*16 + q*4)] = o;
                    }
            }
            __syncthreads();
            // -------- L3 + mix: state = tanh(G2 W2 + b2); GS = A @ state --
            {
                float gs[NODE][4];
                #pragma unroll
                for (int i = 0; i < NODE; ++i)
                    #pragma unroll
                    for (int r = 0; r < 4; ++r) gs[i][r] = 0.f;
                #pragma unroll
                for (int nd = 0; nd < NODE; ++nd) {
                    const int row = nd*16 + ln;
                    half8 a[4];
                    #pragma unroll
                    for (int ks = 0; ks < 4; ++ks)
                        a[ks] = *(const half8*)&sGD[1][swz128(row, ks*32 + k0q)];
                    float4v acc = __builtin_amdgcn_mfma_f32_16x16x32_f16(wf3[0], a[0], b2q, 0,0,0);
                    #pragma unroll
                    for (int ks = 1; ks < 4; ++ks)
                        acc = __builtin_amdgcn_mfma_f32_16x16x32_f16(wf3[ks], a[ks], acc, 0,0,0);
                    float th[4];
                    #pragma unroll
                    for (int r = 0; r < 4; ++r) {
                        float z = acc[r];
                        float e = __expf(-2.f*fabsf(z));
                        th[r] = copysignf((1.f - e)/(1.f + e), z);
                    }
                    if (t == TT-1) {   // raw state straight to xs (once)
                        size_t ob = (size_t)(bbase+ln)*XS_DIM + 5 + nd*64 + w*16 + q*4;
                        #pragma unroll
                        for (int r = 0; r < 4; ++r) xs[ob + r] = th[r];
                    }
                    #pragma unroll
                    for (int r = 0; r < 4; ++r)
                        #pragma unroll
                        for (int i = 0; i < NODE; ++i) gs[i][r] += af[i][nd]*th[r];
                }
                #pragma unroll
                for (int i = 0; i < NODE; ++i) {
                    h16x4 o;
                    #pragma unroll
                    for (int r = 0; r < 4; ++r) o[r] = (h16)gs[i][r];
                    *(h16x4*)&sGS[swz64(i*16+ln, w*16 + q*4)] = o;
                }
            }
            __syncthreads();
        }
    }

    // ---- epilogue: x_end -> xs[b][0..4] ----
    if (tid < NB*NODE) {
        int e = tid / NODE, j = tid - (tid/NODE)*NODE;
        xs[(size_t)(bbase+e)*XS_DIM + j] = (float)sx[1][TB-1][j][e];   // t=511
    }
}

// ---------------------------------------------------------------------------
// Kernel B: h = relu(xs @ fc1_w + fc1_b) + per-column sum/sumsq for BN.
// ---------------------------------------------------------------------------
__global__ __launch_bounds__(256) void fc1_kernel(
    const float* __restrict__ xs, const float* __restrict__ fc1_w,
    const float* __restrict__ fc1_b, float* __restrict__ h,
    float* __restrict__ sums)
{
    __shared__ float s_xs[16*XS_DIM];
    const int tid = threadIdx.x;
    const int r0 = blockIdx.x * 16;
    for (int i = tid; i < 16*XS_DIM; i += 256)
        s_xs[i] = xs[(size_t)r0*XS_DIM + i];
    __syncthreads();

    float acc[16];
    #pragma unroll
    for (int r = 0; r < 16; ++r) acc[r] = 0.f;
    for (int k = 0; k < XS_DIM; ++k) {
        float wv = fc1_w[(size_t)k*H2 + tid];
        #pragma unroll
        for (int r = 0; r < 16; ++r) acc[r] += s_xs[r*XS_DIM + k]*wv;
    }
    float bb = fc1_b[tid];
    float ls = 0.f, lq = 0.f;
    #pragma unroll
    for (int r = 0; r < 16; ++r) {
        float v = fmaxf(acc[r] + bb, 0.f);
        h[(size_t)(r0+r)*H2 + tid] = v;
        ls += v; lq += v*v;
    }
    atomicAdd(&sums[tid], ls);
    atomicAdd(&sums[H2 + tid], lq);
}

// ---------------------------------------------------------------------------
// Kernel C: BN(train) normalize + fc2 + softmax. One wave per row.
// ---------------------------------------------------------------------------
__global__ __launch_bounds__(256) void head_kernel(
    const float* __restrict__ h, const float* __restrict__ sums,
    const float* __restrict__ gamma, const float* __restrict__ beta,
    const float* __restrict__ fc2_w, const float* __restrict__ fc2_b,
    float* __restrict__ out)
{
    const int lane = threadIdx.x & 63;
    const int r = blockIdx.x*4 + (threadIdx.x >> 6);
    const int c0 = lane*4;

    float4 hv = *(const float4*)&h[(size_t)r*H2 + c0];
    float hvv[4] = {hv.x, hv.y, hv.z, hv.w};
    float y[4];
    #pragma unroll
    for (int c = 0; c < 4; ++c) {
        int cc = c0 + c;
        float mean = sums[cc] * (1.f/NBATCH);
        float var  = sums[H2+cc]*(1.f/NBATCH) - mean*mean;
        float rstd = rsqrtf(var + EPS);
        y[c] = (hvv[c] - mean)*rstd*gamma[cc] + beta[cc];
    }
    float lg[7];
    #pragma unroll
    for (int j = 0; j < 7; ++j) {
        float p = 0.f;
        #pragma unroll
        for (int c = 0; c < 4; ++c) p += y[c]*fc2_w[(size_t)(c0+c)*7 + j];
        #pragma unroll
        for (int off = 32; off >= 1; off >>= 1) p += __shfl_xor(p, off, 64);
        lg[j] = p + fc2_b[j];
    }
    if (lane == 0) {
        float m = lg[0];
        #pragma unroll
        for (int j = 1; j < 7; ++j) m = fmaxf(m, lg[j]);
        float ev[7]; float s = 0.f;
        #pragma unroll
        for (int j = 0; j < 7; ++j) { ev[j] = expf(lg[j]-m); s += ev[j]; }
        float inv = 1.f/s;
        #pragma unroll
        for (int j = 0; j < 7; ++j) out[(size_t)r*7 + j] = ev[j]*inv;
    }
}

// ---------------------------------------------------------------------------
extern "C" void kernel_launch(void* const* d_in, const int* in_sizes, int n_in,
                              void* d_out, int out_size, void* d_ws, size_t ws_size,
                              hipStream_t stream)
{
    (void)in_sizes; (void)n_in; (void)out_size; (void)ws_size;
    const float* x     = (const float*)d_in[0];
    const float* adj   = (const float*)d_in[1];
    const float* W0    = (const float*)d_in[2];
    const float* b0    = (const float*)d_in[3];
    const float* W1    = (const float*)d_in[4];
    const float* b1    = (const float*)d_in[5];
    const float* W2    = (const float*)d_in[6];
    const float* b2    = (const float*)d_in[7];
    const float* fc1w  = (const float*)d_in[8];
    const float* fc1b  = (const float*)d_in[9];
    const float* gamma = (const float*)d_in[10];
    const float* beta  = (const float*)d_in[11];
    const float* fc2w  = (const float*)d_in[12];
    const float* fc2b  = (const float*)d_in[13];
    float* out = (float*)d_out;

    char* ws = (char*)d_ws;
    float* xs   = (float*)(ws);                                  // 8192*325 f32
    float* hbuf = (float*)(ws + 10649600);                       // 8192*256 f32
    float* sums = (float*)(ws + 10649600 + 8388608);             // 512 f32

    hipMemsetAsync(sums, 0, 512*sizeof(float), stream);
    rnn_kernel<<<NBATCH/NB, 256, 0, stream>>>(x, adj, W0, b0, W1, b1, W2, b2, xs);
    fc1_kernel<<<NBATCH/16, 256, 0, stream>>>(xs, fc1w, fc1b, hbuf, sums);
    head_kernel<<<NBATCH/4, 256, 0, stream>>>(hbuf, sums, gamma, beta, fc2w, fc2b, out);
}

// Round 7
// 2315.947 us; speedup vs baseline: 3.1266x; 1.1638x over previous
//
#include <hip/hip_runtime.h>
#include <math.h>

#define NODE 5
#define TT 512
#define NBATCH 8192
#define NB 16            // batch elems per block
#define MR (NB*NODE)     // 80 rows (row80 = node*16 + e)
#define TB 32
#define XS_DIM 325
#define H2 256
#define EPS 1e-5f

typedef _Float16 h16;
typedef __attribute__((ext_vector_type(8))) _Float16 half8;
typedef __attribute__((ext_vector_type(4))) _Float16 h16x4;
typedef __attribute__((ext_vector_type(2))) _Float16 half2v;
typedef __attribute__((ext_vector_type(4))) float float4v;

// Swizzle recap (round-5/6 layout, unchanged): half-index hi = row*LDW +
// (hc ^ ((row&7)<<3)). Since every accessed row = k*16 + ln, row&7 == ln&7:
// the XOR is a PER-LANE CONSTANT -> all LDS addresses = per-thread base +
// compile-time byte offset (nd*4096 / nd*2048 / +20480 for GD[1]).
__device__ __forceinline__ float rfl_f(float v) {
    return __uint_as_float(__builtin_amdgcn_readfirstlane(__float_as_uint(v)));
}
// v_cvt_pkrtz_f16_f32: 1 instr packs 2 f32 -> 2 f16 (RTZ; mix inputs only).
__device__ __forceinline__ half2v pkrtz(float a, float b) {
    return __builtin_bit_cast(half2v, __builtin_amdgcn_cvt_pkrtz(a, b));
}
__device__ __forceinline__ half2v pkmax0(half2v v) {
    half2v z; z[0] = (h16)0.f; z[1] = (h16)0.f;
    return __builtin_elementwise_max(v, z);
}

// ---------------------------------------------------------------------------
// RNN kernel, 256 threads (4 waves), row80 = node*16 + e (node-major),
// fused-mix structure (3 barriers/step). Round-7 deltas (VALU-cut only):
//  - tanh divide -> v_rcp_f32 (+1ulp on an f16-cast value)
//  - mix accumulators init with first product (no zero-init v_movs)
//  - all LDS addressing as 7 persistent byte-bases + imm offsets (row&7==ln&7)
//  - L1 relu packed f16 after pkrtz (exact: rtz monotonic, sign-preserving)
// State path (L3 tanh f32 mix, RTE cast to GS) numerically unchanged.
// __launch_bounds__(256,2) => 128-VGPR cap (empirical: rounds 0-1, 5, 6).
// ---------------------------------------------------------------------------
__global__ __launch_bounds__(256, 2) void rnn_kernel(
    const float* __restrict__ x, const float* __restrict__ adj,
    const float* __restrict__ W0, const float* __restrict__ b0,
    const float* __restrict__ W1, const float* __restrict__ b1,
    const float* __restrict__ W2, const float* __restrict__ b2,
    float* __restrict__ xs)
{
    __shared__ __align__(16) h16 sGD[2][MR*128]; // 40960 B (L1 out / L2 out)
    __shared__ __align__(16) h16 sGS[MR*64];     // 10240 B (state, mixed)
    __shared__ h16  sx[2][TB][NODE][16];         // 10240 B (x chunks, dbuf)
    __shared__ float sxg[TB][MR];                // 10240 B (mixed x, per chunk)

    const int tid  = threadIdx.x;
    const int lane = tid & 63;
    const int w    = tid >> 6;       // wave 0..3
    const int ln   = lane & 15;      // col = batch elem e
    const int q    = lane >> 4;      // quad 0..3
    const int k0q  = q*8;
    const int bbase = blockIdx.x * NB;

    // ---- persistent LDS byte-bases (see swizzle recap above) ----
    char* const gd0 = (char*)&sGD[0][0];
    char* const gsB = (char*)&sGS[0];
    const int xorv = (ln & 7) << 3;
    const int rB0 = ln*256 + 2*(( 0 + k0q) ^ xorv);  // GD read, ks even (ks>=2: +128)
    const int rB1 = ln*256 + 2*((32 + k0q) ^ xorv);  // GD read, ks odd
    const int gR0 = ln*128 + 2*(( 0 + k0q) ^ xorv);  // GS read, a0
    const int gR1 = ln*128 + 2*((32 + k0q) ^ xorv);  // GS read, a1
    const int wB0 = ln*256 + 2*(((2*w+0)*16 + q*4) ^ xorv);  // GD write t2=0
    const int wB1 = ln*256 + 2*(((2*w+1)*16 + q*4) ^ xorv);  // GD write t2=1
    const int gW  = ln*128 + 2*((w*16 + q*4) ^ xorv);        // GS write

    // ---- A = adj.T, wave-uniform -> SGPRs (f32 + packed f16 copies) ----
    float  af[NODE][NODE];
    half2v ahp[NODE][NODE];
    #pragma unroll
    for (int i = 0; i < NODE; ++i)
        #pragma unroll
        for (int j = 0; j < NODE; ++j) {
            float v = rfl_f(adj[j*NODE + i]);
            af[i][j] = v;
            h16 hv = (h16)v;
            half2v t; t[0] = hv; t[1] = hv;
            ahp[i][j] = t;
        }

    // ---- weight fragments (VGPRs): two 16-feat tiles per wave (L1/L2),
    //      one (L3). A-frag of W^T: lane holds W[ks*32+q*8+j][feat tile]. ----
    half8 wf0[2][2], wf1f[2][4], wf3[4];
    {
        #pragma unroll
        for (int t2 = 0; t2 < 2; ++t2) {
            int n1 = (2*w+t2)*16 + ln;
            #pragma unroll
            for (int ks = 0; ks < 2; ++ks) {
                half8 f;
                #pragma unroll
                for (int j = 0; j < 8; ++j)
                    f[j] = (h16)W0[(size_t)(1 + ks*32 + k0q + j)*128 + n1]; // rows 1..64
                wf0[t2][ks] = f;
            }
            #pragma unroll
            for (int ks = 0; ks < 4; ++ks) {
                half8 f;
                #pragma unroll
                for (int j = 0; j < 8; ++j)
                    f[j] = (h16)W1[(size_t)(ks*32 + k0q + j)*128 + n1];
                wf1f[t2][ks] = f;
            }
        }
        int n3 = w*16 + ln;
        #pragma unroll
        for (int ks = 0; ks < 4; ++ks) {
            half8 f;
            #pragma unroll
            for (int j = 0; j < 8; ++j)
                f[j] = (h16)W2[(size_t)(ks*32 + k0q + j)*64 + n3];
            wf3[ks] = f;
        }
    }
    // Bias quads (MFMA C-operand init) + W0 row-0 (x rank-1), per out-feature.
    float4v b0q[2], b1q[2], b2q;
    float w0s[2][4];
    #pragma unroll
    for (int t2 = 0; t2 < 2; ++t2)
        #pragma unroll
        for (int r = 0; r < 4; ++r) {
            int fi = (2*w+t2)*16 + q*4 + r;
            b0q[t2][r] = b0[fi];
            w0s[t2][r] = W0[fi];
            b1q[t2][r] = b1[fi];
        }
    #pragma unroll
    for (int r = 0; r < 4; ++r) b2q[r] = b2[w*16 + q*4 + r];

    // ---- prologue: stage x chunk 0, zero initial mixed state ----
    for (int i = tid; i < TB*NODE*16; i += 256) {
        int tl = i & 31; int ne = i >> 5; int n = ne >> 4; int e = ne & 15;
        sx[0][tl][n][e] = (h16)x[((size_t)(bbase+e)*NODE + n)*TT + tl];
    }
    for (int i = tid; i < MR*64; i += 256) sGS[i] = (h16)0.f;
    __syncthreads();

    #pragma unroll 1
    for (int tc = 0; tc < TT/TB; ++tc) {
        const int buf = tc & 1;
        // mixed x for this chunk: sxg[ti][nd*16+e] = sum_j af[nd][j]*x[e][j][t]
        for (int i = tid; i < TB*MR; i += 256) {
            int ti = i / MR, row = i - ti*MR;
            int nd = row >> 4, e = row & 15;
            float acc = 0.f;
            #pragma unroll
            for (int j = 0; j < NODE; ++j)
                acc += af[nd][j] * (float)sx[buf][ti][j][e];
            sxg[ti][row] = acc;
        }
        if (tc+1 < TT/TB) {   // stage next chunk (other buffer)
            for (int i = tid; i < TB*NODE*16; i += 256) {
                int tl = i & 31; int ne = i >> 5; int n = ne >> 4; int e = ne & 15;
                sx[buf^1][tl][n][e] =
                    (h16)x[((size_t)(bbase+e)*NODE + n)*TT + (tc+1)*TB + tl];
            }
        }
        __syncthreads();

        #pragma unroll 1
        for (int tt = 0; tt < TB; ++tt) {
            const int t = tc*TB + tt;
            const float* sxp = &sxg[tt][ln];
            // -------- L1 + mix: G1 = A @ relu([x|gS] W0 + b0) -------------
            {
                half2v g[2][NODE][2];
                #pragma unroll
                for (int nd = 0; nd < NODE; ++nd) {
                    half8 a0 = *(const half8*)(gsB + gR0 + nd*2048);
                    half8 a1 = *(const half8*)(gsB + gR1 + nd*2048);
                    float xg = sxp[nd*16];
                    #pragma unroll
                    for (int t2 = 0; t2 < 2; ++t2) {
                        float4v acc = __builtin_amdgcn_mfma_f32_16x16x32_f16(wf0[t2][0], a0, b0q[t2], 0,0,0);
                        acc = __builtin_amdgcn_mfma_f32_16x16x32_f16(wf0[t2][1], a1, acc, 0,0,0);
                        float v0 = fmaf(xg, w0s[t2][0], acc[0]);
                        float v1 = fmaf(xg, w0s[t2][1], acc[1]);
                        float v2 = fmaf(xg, w0s[t2][2], acc[2]);
                        float v3 = fmaf(xg, w0s[t2][3], acc[3]);
                        half2v p0 = pkmax0(pkrtz(v0, v1));
                        half2v p1 = pkmax0(pkrtz(v2, v3));
                        if (nd == 0) {
                            #pragma unroll
                            for (int i = 0; i < NODE; ++i) {
                                g[t2][i][0] = ahp[i][0]*p0;
                                g[t2][i][1] = ahp[i][0]*p1;
                            }
                        } else {
                            #pragma unroll
                            for (int i = 0; i < NODE; ++i) {
                                g[t2][i][0] += ahp[i][nd]*p0;
                                g[t2][i][1] += ahp[i][nd]*p1;
                            }
                        }
                    }
                }
                #pragma unroll
                for (int t2 = 0; t2 < 2; ++t2)
                    #pragma unroll
                    for (int i = 0; i < NODE; ++i) {
                        h16x4 o;
                        o[0]=g[t2][i][0][0]; o[1]=g[t2][i][0][1];
                        o[2]=g[t2][i][1][0]; o[3]=g[t2][i][1][1];
                        *(h16x4*)(gd0 + (t2 ? wB1 : wB0) + i*4096) = o;
                    }
            }
            __syncthreads();
            // -------- L2 + mix: G2 = A @ relu(G1 W1 + b1) -----------------
            {
                half2v g[2][NODE][2];
                #pragma unroll
                for (int nd = 0; nd < NODE; ++nd) {
                    half8 a[4];
                    a[0] = *(const half8*)(gd0 + rB0 +       nd*4096);
                    a[1] = *(const half8*)(gd0 + rB1 +       nd*4096);
                    a[2] = *(const half8*)(gd0 + rB0 + 128 + nd*4096);
                    a[3] = *(const half8*)(gd0 + rB1 + 128 + nd*4096);
                    #pragma unroll
                    for (int t2 = 0; t2 < 2; ++t2) {
                        float4v acc = __builtin_amdgcn_mfma_f32_16x16x32_f16(wf1f[t2][0], a[0], b1q[t2], 0,0,0);
                        #pragma unroll
                        for (int ks = 1; ks < 4; ++ks)
                            acc = __builtin_amdgcn_mfma_f32_16x16x32_f16(wf1f[t2][ks], a[ks], acc, 0,0,0);
                        half2v p0 = pkmax0(pkrtz(acc[0], acc[1]));
                        half2v p1 = pkmax0(pkrtz(acc[2], acc[3]));
                        if (nd == 0) {
                            #pragma unroll
                            for (int i = 0; i < NODE; ++i) {
                                g[t2][i][0] = ahp[i][0]*p0;
                                g[t2][i][1] = ahp[i][0]*p1;
                            }
                        } else {
                            #pragma unroll
                            for (int i = 0; i < NODE; ++i) {
                                g[t2][i][0] += ahp[i][nd]*p0;
                                g[t2][i][1] += ahp[i][nd]*p1;
                            }
                        }
                    }
                }
                #pragma unroll
                for (int t2 = 0; t2 < 2; ++t2)
                    #pragma unroll
                    for (int i = 0; i < NODE; ++i) {
                        h16x4 o;
                        o[0]=g[t2][i][0][0]; o[1]=g[t2][i][0][1];
                        o[2]=g[t2][i][1][0]; o[3]=g[t2][i][1][1];
                        *(h16x4*)(gd0 + 20480 + (t2 ? wB1 : wB0) + i*4096) = o;
                    }
            }
            __syncthreads();
            // -------- L3 + mix: state = tanh(G2 W2 + b2); GS = A @ state --
            {
                const bool last = (t == TT-1);
                float gs[NODE][4];
                #pragma unroll
                for (int nd = 0; nd < NODE; ++nd) {
                    half8 a[4];
                    a[0] = *(const half8*)(gd0 + 20480 + rB0 +       nd*4096);
                    a[1] = *(const half8*)(gd0 + 20480 + rB1 +       nd*4096);
                    a[2] = *(const half8*)(gd0 + 20480 + rB0 + 128 + nd*4096);
                    a[3] = *(const half8*)(gd0 + 20480 + rB1 + 128 + nd*4096);
                    float4v acc = __builtin_amdgcn_mfma_f32_16x16x32_f16(wf3[0], a[0], b2q, 0,0,0);
                    #pragma unroll
                    for (int ks = 1; ks < 4; ++ks)
                        acc = __builtin_amdgcn_mfma_f32_16x16x32_f16(wf3[ks], a[ks], acc, 0,0,0);
                    float th[4];
                    #pragma unroll
                    for (int r = 0; r < 4; ++r) {
                        float z = acc[r];
                        float e = __expf(-2.f*fabsf(z));
                        float rc = __builtin_amdgcn_rcpf(1.f + e);
                        th[r] = copysignf((1.f - e)*rc, z);
                    }
                    if (last) {   // raw state straight to xs (once)
                        size_t ob = (size_t)(bbase+ln)*XS_DIM + 5 + nd*64 + w*16 + q*4;
                        #pragma unroll
                        for (int r = 0; r < 4; ++r) xs[ob + r] = th[r];
                    }
                    if (nd == 0) {
                        #pragma unroll
                        for (int r = 0; r < 4; ++r)
                            #pragma unroll
                            for (int i = 0; i < NODE; ++i) gs[i][r] = af[i][0]*th[r];
                    } else {
                        #pragma unroll
                        for (int r = 0; r < 4; ++r)
                            #pragma unroll
                            for (int i = 0; i < NODE; ++i) gs[i][r] += af[i][nd]*th[r];
                    }
                }
                #pragma unroll
                for (int i = 0; i < NODE; ++i) {
                    h16x4 o;
                    #pragma unroll
                    for (int r = 0; r < 4; ++r) o[r] = (h16)gs[i][r];
                    *(h16x4*)(gsB + gW + i*2048) = o;
                }
            }
            __syncthreads();
        }
    }

    // ---- epilogue: x_end -> xs[b][0..4] ----
    if (tid < NB*NODE) {
        int e = tid / NODE, j = tid - (tid/NODE)*NODE;
        xs[(size_t)(bbase+e)*XS_DIM + j] = (float)sx[1][TB-1][j][e];   // t=511
    }
}

// ---------------------------------------------------------------------------
// Kernel B: h = relu(xs @ fc1_w + fc1_b) + per-column sum/sumsq for BN.
// ---------------------------------------------------------------------------
__global__ __launch_bounds__(256) void fc1_kernel(
    const float* __restrict__ xs, const float* __restrict__ fc1_w,
    const float* __restrict__ fc1_b, float* __restrict__ h,
    float* __restrict__ sums)
{
    __shared__ float s_xs[16*XS_DIM];
    const int tid = threadIdx.x;
    const int r0 = blockIdx.x * 16;
    for (int i = tid; i < 16*XS_DIM; i += 256)
        s_xs[i] = xs[(size_t)r0*XS_DIM + i];
    __syncthreads();

    float acc[16];
    #pragma unroll
    for (int r = 0; r < 16; ++r) acc[r] = 0.f;
    for (int k = 0; k < XS_DIM; ++k) {
        float wv = fc1_w[(size_t)k*H2 + tid];
        #pragma unroll
        for (int r = 0; r < 16; ++r) acc[r] += s_xs[r*XS_DIM + k]*wv;
    }
    float bb = fc1_b[tid];
    float ls = 0.f, lq = 0.f;
    #pragma unroll
    for (int r = 0; r < 16; ++r) {
        float v = fmaxf(acc[r] + bb, 0.f);
        h[(size_t)(r0+r)*H2 + tid] = v;
        ls += v; lq += v*v;
    }
    atomicAdd(&sums[tid], ls);
    atomicAdd(&sums[H2 + tid], lq);
}

// ---------------------------------------------------------------------------
// Kernel C: BN(train) normalize + fc2 + softmax. One wave per row.
// ---------------------------------------------------------------------------
__global__ __launch_bounds__(256) void head_kernel(
    const float* __restrict__ h, const float* __restrict__ sums,
    const float* __restrict__ gamma, const float* __restrict__ beta,
    const float* __restrict__ fc2_w, const float* __restrict__ fc2_b,
    float* __restrict__ out)
{
    const int lane = threadIdx.x & 63;
    const int r = blockIdx.x*4 + (threadIdx.x >> 6);
    const int c0 = lane*4;

    float4 hv = *(const float4*)&h[(size_t)r*H2 + c0];
    float hvv[4] = {hv.x, hv.y, hv.z, hv.w};
    float y[4];
    #pragma unroll
    for (int c = 0; c < 4; ++c) {
        int cc = c0 + c;
        float mean = sums[cc] * (1.f/NBATCH);
        float var  = sums[H2+cc]*(1.f/NBATCH) - mean*mean;
        float rstd = rsqrtf(var + EPS);
        y[c] = (hvv[c] - mean)*rstd*gamma[cc] + beta[cc];
    }
    float lg[7];
    #pragma unroll
    for (int j = 0; j < 7; ++j) {
        float p = 0.f;
        #pragma unroll
        for (int c = 0; c < 4; ++c) p += y[c]*fc2_w[(size_t)(c0+c)*7 + j];
        #pragma unroll
        for (int off = 32; off >= 1; off >>= 1) p += __shfl_xor(p, off, 64);
        lg[j] = p + fc2_b[j];
    }
    if (lane == 0) {
        float m = lg[0];
        #pragma unroll
        for (int j = 1; j < 7; ++j) m = fmaxf(m, lg[j]);
        float ev[7]; float s = 0.f;
        #pragma unroll
        for (int j = 0; j < 7; ++j) { ev[j] = expf(lg[j]-m); s += ev[j]; }
        float inv = 1.f/s;
        #pragma unroll
        for (int j = 0; j < 7; ++j) out[(size_t)r*7 + j] = ev[j]*inv;
    }
}

// ---------------------------------------------------------------------------
extern "C" void kernel_launch(void* const* d_in, const int* in_sizes, int n_in,
                              void* d_out, int out_size, void* d_ws, size_t ws_size,
                              hipStream_t stream)
{
    (void)in_sizes; (void)n_in; (void)out_size; (void)ws_size;
    const float* x     = (const float*)d_in[0];
    const float* adj   = (const float*)d_in[1];
    const float* W0    = (const float*)d_in[2];
    const float* b0    = (const float*)d_in[3];
    const float* W1    = (const float*)d_in[4];
    const float* b1    = (const float*)d_in[5];
    const float* W2    = (const float*)d_in[6];
    const float* b2    = (const float*)d_in[7];
    const float* fc1w  = (const float*)d_in[8];
    const float* fc1b  = (const float*)d_in[9];
    const float* gamma = (const float*)d_in[10];
    const float* beta  = (const float*)d_in[11];
    const float* fc2w  = (const float*)d_in[12];
    const float* fc2b  = (const float*)d_in[13];
    float* out = (float*)d_out;

    char* ws = (char*)d_ws;
    float* xs   = (float*)(ws);                                  // 8192*325 f32
    float* hbuf = (float*)(ws + 10649600);                       // 8192*256 f32
    float* sums = (float*)(ws + 10649600 + 8388608);             // 512 f32

    hipMemsetAsync(sums, 0, 512*sizeof(float), stream);
    rnn_kernel<<<NBATCH/NB, 256, 0, stream>>>(x, adj, W0, b0, W1, b1, W2, b2, xs);
    fc1_kernel<<<NBATCH/16, 256, 0, stream>>>(xs, fc1w, fc1b, hbuf, sums);
    head_kernel<<<NBATCH/4, 256, 0, stream>>>(hbuf, sums, gamma, beta, fc2w, fc2b, out);
}

// Round 9
// 2193.205 us; speedup vs baseline: 3.3016x; 1.0560x over previous
//
#include <hip/hip_runtime.h>
#include <math.h>

#define NODE 5
#define TT 512
#define NBATCH 8192
#define NB 16            // batch elems per block
#define MR (NB*NODE)     // 80 rows (row80 = node*16 + e)
#define TB 32
#define XS_DIM 325
#define H2 256
#define EPS 1e-5f

typedef _Float16 h16;
typedef __attribute__((ext_vector_type(8))) _Float16 half8;
typedef __attribute__((ext_vector_type(4))) _Float16 h16x4;
typedef __attribute__((ext_vector_type(2))) _Float16 half2v;
typedef __attribute__((ext_vector_type(4))) float float4v;

// Swizzle recap (unchanged since round 5): half-index hi = row*LDW +
// (hc ^ ((row&7)<<3)). Every accessed row = k*16 + ln, so row&7 == ln&7:
// the XOR is a PER-LANE CONSTANT -> all LDS addresses = per-thread base +
// compile-time byte offset (nd*4096 / nd*2048 / +20480 for GD[1]).
__device__ __forceinline__ float rfl_f(float v) {
    return __uint_as_float(__builtin_amdgcn_readfirstlane(__float_as_uint(v)));
}
// v_cvt_pkrtz_f16_f32: 1 instr packs 2 f32 -> 2 f16 (RTZ; mix inputs only).
__device__ __forceinline__ half2v pkrtz(float a, float b) {
    return __builtin_bit_cast(half2v, __builtin_amdgcn_cvt_pkrtz(a, b));
}
__device__ __forceinline__ half2v pkmax0(half2v v) {
    half2v z; z[0] = (h16)0.f; z[1] = (h16)0.f;
    return __builtin_elementwise_max(v, z);
}

// ---------------------------------------------------------------------------
// RNN kernel, 256 threads (4 waves), row80 = node*16 + e (node-major),
// fused-mix structure (3 barriers/step). Round-9 = round-8 with the compile
// fix (__exp2f -> __builtin_amdgcn_exp2f, the raw v_exp_f32):
//  - x rank-1 term folded into the MFMA K-dim: 3rd chain link with A-frag
//    wf0x (= W0 row 0 at k-slot 64, else 0) and B-frag a2 (= xg f16 at q==0
//    lanes, else 0), bias as its C-in. Removes 8 v_fma + 1 b32 read per nd.
//  - sxg stored as f16 (pre-converted in the chunk pass)
//  - tanh: med3-clamp(+-9) + v_exp_f32 + rcp symmetric form (no abs/copysign)
//  - s_setprio(1) around L1/L2 MFMA loops (L3 stays 0: VALU-heavy, lets the
//    other block's MFMA phases win issue arbitration — 2 indep blocks/CU)
// __launch_bounds__(256,2) => 128-VGPR cap (empirical: rounds 0-1, 5-7).
// ---------------------------------------------------------------------------
__global__ __launch_bounds__(256, 2) void rnn_kernel(
    const float* __restrict__ x, const float* __restrict__ adj,
    const float* __restrict__ W0, const float* __restrict__ b0,
    const float* __restrict__ W1, const float* __restrict__ b1,
    const float* __restrict__ W2, const float* __restrict__ b2,
    float* __restrict__ xs)
{
    __shared__ __align__(16) h16 sGD[2][MR*128]; // 40960 B (L1 out / L2 out)
    __shared__ __align__(16) h16 sGS[MR*64];     // 10240 B (state, mixed)
    __shared__ h16  sx[2][TB][NODE][16];         // 10240 B (x chunks, dbuf)
    __shared__ h16  sxg[TB][MR];                 //  5120 B (mixed x, f16)

    const int tid  = threadIdx.x;
    const int lane = tid & 63;
    const int w    = tid >> 6;       // wave 0..3
    const int ln   = lane & 15;      // col = batch elem e
    const int q    = lane >> 4;      // quad 0..3
    const int k0q  = q*8;
    const int bbase = blockIdx.x * NB;

    // ---- persistent LDS byte-bases (see swizzle recap above) ----
    char* const gd0 = (char*)&sGD[0][0];
    char* const gsB = (char*)&sGS[0];
    const int xorv = (ln & 7) << 3;
    const int rB0 = ln*256 + 2*(( 0 + k0q) ^ xorv);  // GD read, ks even (ks>=2: +128)
    const int rB1 = ln*256 + 2*((32 + k0q) ^ xorv);  // GD read, ks odd
    const int gR0 = ln*128 + 2*(( 0 + k0q) ^ xorv);  // GS read, a0
    const int gR1 = ln*128 + 2*((32 + k0q) ^ xorv);  // GS read, a1
    const int wB0 = ln*256 + 2*(((2*w+0)*16 + q*4) ^ xorv);  // GD write t2=0
    const int wB1 = ln*256 + 2*(((2*w+1)*16 + q*4) ^ xorv);  // GD write t2=1
    const int gW  = ln*128 + 2*((w*16 + q*4) ^ xorv);        // GS write

    // ---- A = adj.T, wave-uniform -> SGPRs (f32 + packed f16 copies) ----
    float  af[NODE][NODE];
    half2v ahp[NODE][NODE];
    #pragma unroll
    for (int i = 0; i < NODE; ++i)
        #pragma unroll
        for (int j = 0; j < NODE; ++j) {
            float v = rfl_f(adj[j*NODE + i]);
            af[i][j] = v;
            h16 hv = (h16)v;
            half2v t; t[0] = hv; t[1] = hv;
            ahp[i][j] = t;
        }

    // ---- weight fragments (VGPRs): two 16-feat tiles per wave (L1/L2),
    //      one (L3). A-frag of W^T: lane holds W[ks*32+q*8+j][feat tile]. ----
    half8 wf0[2][2], wf0x[2], wf1f[2][4], wf3[4];
    {
        #pragma unroll
        for (int t2 = 0; t2 < 2; ++t2) {
            int n1 = (2*w+t2)*16 + ln;
            #pragma unroll
            for (int ks = 0; ks < 2; ++ks) {
                half8 f;
                #pragma unroll
                for (int j = 0; j < 8; ++j)
                    f[j] = (h16)W0[(size_t)(1 + ks*32 + k0q + j)*128 + n1]; // rows 1..64
                wf0[t2][ks] = f;
            }
            // x-block A-frag: k-slot 64 (q==0, j==0) = W0 row 0, else 0
            {
                half8 f;
                #pragma unroll
                for (int j = 0; j < 8; ++j) f[j] = (h16)0.f;
                if (q == 0) f[0] = (h16)W0[n1];
                wf0x[t2] = f;
            }
            #pragma unroll
            for (int ks = 0; ks < 4; ++ks) {
                half8 f;
                #pragma unroll
                for (int j = 0; j < 8; ++j)
                    f[j] = (h16)W1[(size_t)(ks*32 + k0q + j)*128 + n1];
                wf1f[t2][ks] = f;
            }
        }
        int n3 = w*16 + ln;
        #pragma unroll
        for (int ks = 0; ks < 4; ++ks) {
            half8 f;
            #pragma unroll
            for (int j = 0; j < 8; ++j)
                f[j] = (h16)W2[(size_t)(ks*32 + k0q + j)*64 + n3];
            wf3[ks] = f;
        }
    }
    // Bias quads (MFMA C-operand init), per out-feature.
    float4v b0q[2], b1q[2], b2q;
    #pragma unroll
    for (int t2 = 0; t2 < 2; ++t2)
        #pragma unroll
        for (int r = 0; r < 4; ++r) {
            int fi = (2*w+t2)*16 + q*4 + r;
            b0q[t2][r] = b0[fi];
            b1q[t2][r] = b1[fi];
        }
    #pragma unroll
    for (int r = 0; r < 4; ++r) b2q[r] = b2[w*16 + q*4 + r];

    // ---- prologue: stage x chunk 0, zero initial mixed state ----
    for (int i = tid; i < TB*NODE*16; i += 256) {
        int tl = i & 31; int ne = i >> 5; int n = ne >> 4; int e = ne & 15;
        sx[0][tl][n][e] = (h16)x[((size_t)(bbase+e)*NODE + n)*TT + tl];
    }
    for (int i = tid; i < MR*64; i += 256) sGS[i] = (h16)0.f;
    __syncthreads();

    #pragma unroll 1
    for (int tc = 0; tc < TT/TB; ++tc) {
        const int buf = tc & 1;
        // mixed x for this chunk (f16): sxg[ti][nd*16+e] = sum_j af[nd][j]*x
        for (int i = tid; i < TB*MR; i += 256) {
            int ti = i / MR, row = i - ti*MR;
            int nd = row >> 4, e = row & 15;
            float acc = 0.f;
            #pragma unroll
            for (int j = 0; j < NODE; ++j)
                acc += af[nd][j] * (float)sx[buf][ti][j][e];
            sxg[ti][row] = (h16)acc;
        }
        if (tc+1 < TT/TB) {   // stage next chunk (other buffer)
            for (int i = tid; i < TB*NODE*16; i += 256) {
                int tl = i & 31; int ne = i >> 5; int n = ne >> 4; int e = ne & 15;
                sx[buf^1][tl][n][e] =
                    (h16)x[((size_t)(bbase+e)*NODE + n)*TT + (tc+1)*TB + tl];
            }
        }
        __syncthreads();

        #pragma unroll 1
        for (int tt = 0; tt < TB; ++tt) {
            const int t = tc*TB + tt;
            // -------- L1 + mix: G1 = A @ relu([x|gS] W0 + b0) -------------
            {
                half2v g[2][NODE][2];
                __builtin_amdgcn_s_setprio(1);
                #pragma unroll
                for (int nd = 0; nd < NODE; ++nd) {
                    half8 a0 = *(const half8*)(gsB + gR0 + nd*2048);
                    half8 a1 = *(const half8*)(gsB + gR1 + nd*2048);
                    // B-frag for the x k-block: slot 64 (q==0,j==0) = xg
                    h16 xgv = sxg[tt][nd*16 + ln];
                    half8 a2;
                    #pragma unroll
                    for (int j = 0; j < 8; ++j) a2[j] = (h16)0.f;
                    if (q == 0) a2[0] = xgv;
                    #pragma unroll
                    for (int t2 = 0; t2 < 2; ++t2) {
                        float4v acc = __builtin_amdgcn_mfma_f32_16x16x32_f16(wf0x[t2], a2, b0q[t2], 0,0,0);
                        acc = __builtin_amdgcn_mfma_f32_16x16x32_f16(wf0[t2][0], a0, acc, 0,0,0);
                        acc = __builtin_amdgcn_mfma_f32_16x16x32_f16(wf0[t2][1], a1, acc, 0,0,0);
                        half2v p0 = pkmax0(pkrtz(acc[0], acc[1]));
                        half2v p1 = pkmax0(pkrtz(acc[2], acc[3]));
                        if (nd == 0) {
                            #pragma unroll
                            for (int i = 0; i < NODE; ++i) {
                                g[t2][i][0] = ahp[i][0]*p0;
                                g[t2][i][1] = ahp[i][0]*p1;
                            }
                        } else {
                            #pragma unroll
                            for (int i = 0; i < NODE; ++i) {
                                g[t2][i][0] += ahp[i][nd]*p0;
                                g[t2][i][1] += ahp[i][nd]*p1;
                            }
                        }
                    }
                }
                __builtin_amdgcn_s_setprio(0);
                #pragma unroll
                for (int t2 = 0; t2 < 2; ++t2)
                    #pragma unroll
                    for (int i = 0; i < NODE; ++i) {
                        h16x4 o;
                        o[0]=g[t2][i][0][0]; o[1]=g[t2][i][0][1];
                        o[2]=g[t2][i][1][0]; o[3]=g[t2][i][1][1];
                        *(h16x4*)(gd0 + (t2 ? wB1 : wB0) + i*4096) = o;
                    }
            }
            __syncthreads();
            // -------- L2 + mix: G2 = A @ relu(G1 W1 + b1) -----------------
            {
                half2v g[2][NODE][2];
                __builtin_amdgcn_s_setprio(1);
                #pragma unroll
                for (int nd = 0; nd < NODE; ++nd) {
                    half8 a[4];
                    a[0] = *(const half8*)(gd0 + rB0 +       nd*4096);
                    a[1] = *(const half8*)(gd0 + rB1 +       nd*4096);
                    a[2] = *(const half8*)(gd0 + rB0 + 128 + nd*4096);
                    a[3] = *(const half8*)(gd0 + rB1 + 128 + nd*4096);
                    #pragma unroll
                    for (int t2 = 0; t2 < 2; ++t2) {
                        float4v acc = __builtin_amdgcn_mfma_f32_16x16x32_f16(wf1f[t2][0], a[0], b1q[t2], 0,0,0);
                        #pragma unroll
                        for (int ks = 1; ks < 4; ++ks)
                            acc = __builtin_amdgcn_mfma_f32_16x16x32_f16(wf1f[t2][ks], a[ks], acc, 0,0,0);
                        half2v p0 = pkmax0(pkrtz(acc[0], acc[1]));
                        half2v p1 = pkmax0(pkrtz(acc[2], acc[3]));
                        if (nd == 0) {
                            #pragma unroll
                            for (int i = 0; i < NODE; ++i) {
                                g[t2][i][0] = ahp[i][0]*p0;
                                g[t2][i][1] = ahp[i][0]*p1;
                            }
                        } else {
                            #pragma unroll
                            for (int i = 0; i < NODE; ++i) {
                                g[t2][i][0] += ahp[i][nd]*p0;
                                g[t2][i][1] += ahp[i][nd]*p1;
                            }
                        }
                    }
                }
                __builtin_amdgcn_s_setprio(0);
                #pragma unroll
                for (int t2 = 0; t2 < 2; ++t2)
                    #pragma unroll
                    for (int i = 0; i < NODE; ++i) {
                        h16x4 o;
                        o[0]=g[t2][i][0][0]; o[1]=g[t2][i][0][1];
                        o[2]=g[t2][i][1][0]; o[3]=g[t2][i][1][1];
                        *(h16x4*)(gd0 + 20480 + (t2 ? wB1 : wB0) + i*4096) = o;
                    }
            }
            __syncthreads();
            // -------- L3 + mix: state = tanh(G2 W2 + b2); GS = A @ state --
            {
                const bool last = (t == TT-1);
                float gs[NODE][4];
                #pragma unroll
                for (int nd = 0; nd < NODE; ++nd) {
                    half8 a[4];
                    a[0] = *(const half8*)(gd0 + 20480 + rB0 +       nd*4096);
                    a[1] = *(const half8*)(gd0 + 20480 + rB1 +       nd*4096);
                    a[2] = *(const half8*)(gd0 + 20480 + rB0 + 128 + nd*4096);
                    a[3] = *(const half8*)(gd0 + 20480 + rB1 + 128 + nd*4096);
                    float4v acc = __builtin_amdgcn_mfma_f32_16x16x32_f16(wf3[0], a[0], b2q, 0,0,0);
                    #pragma unroll
                    for (int ks = 1; ks < 4; ++ks)
                        acc = __builtin_amdgcn_mfma_f32_16x16x32_f16(wf3[ks], a[ks], acc, 0,0,0);
                    float th[4];
                    #pragma unroll
                    for (int r = 0; r < 4; ++r) {
                        // tanh(z) = (E-1)/(E+1), E = 2^(2*log2e*clamp(z,±9))
                        float zc = __builtin_amdgcn_fmed3f(acc[r], -9.f, 9.f);
                        float E  = __builtin_amdgcn_exp2f(zc * 2.885390082f);
                        th[r] = (E - 1.f) * __builtin_amdgcn_rcpf(E + 1.f);
                    }
                    if (last) {   // raw state straight to xs (once)
                        size_t ob = (size_t)(bbase+ln)*XS_DIM + 5 + nd*64 + w*16 + q*4;
                        #pragma unroll
                        for (int r = 0; r < 4; ++r) xs[ob + r] = th[r];
                    }
                    if (nd == 0) {
                        #pragma unroll
                        for (int r = 0; r < 4; ++r)
                            #pragma unroll
                            for (int i = 0; i < NODE; ++i) gs[i][r] = af[i][0]*th[r];
                    } else {
                        #pragma unroll
                        for (int r = 0; r < 4; ++r)
                            #pragma unroll
                            for (int i = 0; i < NODE; ++i) gs[i][r] += af[i][nd]*th[r];
                    }
                }
                #pragma unroll
                for (int i = 0; i < NODE; ++i) {
                    h16x4 o;
                    #pragma unroll
                    for (int r = 0; r < 4; ++r) o[r] = (h16)gs[i][r];
                    *(h16x4*)(gsB + gW + i*2048) = o;
                }
            }
            __syncthreads();
        }
    }

    // ---- epilogue: x_end -> xs[b][0..4] ----
    if (tid < NB*NODE) {
        int e = tid / NODE, j = tid - (tid/NODE)*NODE;
        xs[(size_t)(bbase+e)*XS_DIM + j] = (float)sx[1][TB-1][j][e];   // t=511
    }
}

// ---------------------------------------------------------------------------
// Kernel B: h = relu(xs @ fc1_w + fc1_b) + per-column sum/sumsq for BN.
// ---------------------------------------------------------------------------
__global__ __launch_bounds__(256) void fc1_kernel(
    const float* __restrict__ xs, const float* __restrict__ fc1_w,
    const float* __restrict__ fc1_b, float* __restrict__ h,
    float* __restrict__ sums)
{
    __shared__ float s_xs[16*XS_DIM];
    const int tid = threadIdx.x;
    const int r0 = blockIdx.x * 16;
    for (int i = tid; i < 16*XS_DIM; i += 256)
        s_xs[i] = xs[(size_t)r0*XS_DIM + i];
    __syncthreads();

    float acc[16];
    #pragma unroll
    for (int r = 0; r < 16; ++r) acc[r] = 0.f;
    for (int k = 0; k < XS_DIM; ++k) {
        float wv = fc1_w[(size_t)k*H2 + tid];
        #pragma unroll
        for (int r = 0; r < 16; ++r) acc[r] += s_xs[r*XS_DIM + k]*wv;
    }
    float bb = fc1_b[tid];
    float ls = 0.f, lq = 0.f;
    #pragma unroll
    for (int r = 0; r < 16; ++r) {
        float v = fmaxf(acc[r] + bb, 0.f);
        h[(size_t)(r0+r)*H2 + tid] = v;
        ls += v; lq += v*v;
    }
    atomicAdd(&sums[tid], ls);
    atomicAdd(&sums[H2 + tid], lq);
}

// ---------------------------------------------------------------------------
// Kernel C: BN(train) normalize + fc2 + softmax. One wave per row.
// ---------------------------------------------------------------------------
__global__ __launch_bounds__(256) void head_kernel(
    const float* __restrict__ h, const float* __restrict__ sums,
    const float* __restrict__ gamma, const float* __restrict__ beta,
    const float* __restrict__ fc2_w, const float* __restrict__ fc2_b,
    float* __restrict__ out)
{
    const int lane = threadIdx.x & 63;
    const int r = blockIdx.x*4 + (threadIdx.x >> 6);
    const int c0 = lane*4;

    float4 hv = *(const float4*)&h[(size_t)r*H2 + c0];
    float hvv[4] = {hv.x, hv.y, hv.z, hv.w};
    float y[4];
    #pragma unroll
    for (int c = 0; c < 4; ++c) {
        int cc = c0 + c;
        float mean = sums[cc] * (1.f/NBATCH);
        float var  = sums[H2+cc]*(1.f/NBATCH) - mean*mean;
        float rstd = rsqrtf(var + EPS);
        y[c] = (hvv[c] - mean)*rstd*gamma[cc] + beta[cc];
    }
    float lg[7];
    #pragma unroll
    for (int j = 0; j < 7; ++j) {
        float p = 0.f;
        #pragma unroll
        for (int c = 0; c < 4; ++c) p += y[c]*fc2_w[(size_t)(c0+c)*7 + j];
        #pragma unroll
        for (int off = 32; off >= 1; off >>= 1) p += __shfl_xor(p, off, 64);
        lg[j] = p + fc2_b[j];
    }
    if (lane == 0) {
        float m = lg[0];
        #pragma unroll
        for (int j = 1; j < 7; ++j) m = fmaxf(m, lg[j]);
        float ev[7]; float s = 0.f;
        #pragma unroll
        for (int j = 0; j < 7; ++j) { ev[j] = expf(lg[j]-m); s += ev[j]; }
        float inv = 1.f/s;
        #pragma unroll
        for (int j = 0; j < 7; ++j) out[(size_t)r*7 + j] = ev[j]*inv;
    }
}

// ---------------------------------------------------------------------------
extern "C" void kernel_launch(void* const* d_in, const int* in_sizes, int n_in,
                              void* d_out, int out_size, void* d_ws, size_t ws_size,
                              hipStream_t stream)
{
    (void)in_sizes; (void)n_in; (void)out_size; (void)ws_size;
    const float* x     = (const float*)d_in[0];
    const float* adj   = (const float*)d_in[1];
    const float* W0    = (const float*)d_in[2];
    const float* b0    = (const float*)d_in[3];
    const float* W1    = (const float*)d_in[4];
    const float* b1    = (const float*)d_in[5];
    const float* W2    = (const float*)d_in[6];
    const float* b2    = (const float*)d_in[7];
    const float* fc1w  = (const float*)d_in[8];
    const float* fc1b  = (const float*)d_in[9];
    const float* gamma = (const float*)d_in[10];
    const float* beta  = (const float*)d_in[11];
    const float* fc2w  = (const float*)d_in[12];
    const float* fc2b  = (const float*)d_in[13];
    float* out = (float*)d_out;

    char* ws = (char*)d_ws;
    float* xs   = (float*)(ws);                                  // 8192*325 f32
    float* hbuf = (float*)(ws + 10649600);                       // 8192*256 f32
    float* sums = (float*)(ws + 10649600 + 8388608);             // 512 f32

    hipMemsetAsync(sums, 0, 512*sizeof(float), stream);
    rnn_kernel<<<NBATCH/NB, 256, 0, stream>>>(x, adj, W0, b0, W1, b1, W2, b2, xs);
    fc1_kernel<<<NBATCH/16, 256, 0, stream>>>(xs, fc1w, fc1b, hbuf, sums);
    head_kernel<<<NBATCH/4, 256, 0, stream>>>(hbuf, sums, gamma, beta, fc2w, fc2b, out);
}

// Round 11
// 2189.839 us; speedup vs baseline: 3.3067x; 1.0015x over previous
//
#include <hip/hip_runtime.h>
#include <math.h>

#define NODE 5
#define TT 512
#define NBATCH 8192
#define NB 16            // batch elems per block
#define MR (NB*NODE)     // 80 rows (row80 = node*16 + e)
#define TB 32
#define XS_DIM 325
#define H2 256
#define EPS 1e-5f

typedef _Float16 h16;
typedef __attribute__((ext_vector_type(8))) _Float16 half8;
typedef __attribute__((ext_vector_type(4))) _Float16 h16x4;
typedef __attribute__((ext_vector_type(2))) _Float16 half2v;
typedef __attribute__((ext_vector_type(4))) float float4v;

// Swizzle recap (unchanged since round 5): half-index hi = row*LDW +
// (hc ^ ((row&7)<<3)). Every accessed row = k*16 + ln, so row&7 == ln&7:
// the XOR is a PER-LANE CONSTANT -> all LDS addresses = per-thread base +
// compile-time byte offset (nd*4096 / nd*2048 / +20480 for GD[1]).
__device__ __forceinline__ float rfl_f(float v) {
    return __uint_as_float(__builtin_amdgcn_readfirstlane(__float_as_uint(v)));
}
// v_cvt_pkrtz_f16_f32: 1 instr packs 2 f32 -> 2 f16 (RTZ; mix inputs only).
__device__ __forceinline__ half2v pkrtz(float a, float b) {
    return __builtin_bit_cast(half2v, __builtin_amdgcn_cvt_pkrtz(a, b));
}
__device__ __forceinline__ half2v pkmax0(half2v v) {
    half2v z; z[0] = (h16)0.f; z[1] = (h16)0.f;
    return __builtin_elementwise_max(v, z);
}

// ---------------------------------------------------------------------------
// RNN kernel, 256 threads (4 waves), row80 = node*16 + e (node-major),
// fused-mix structure (3 barriers/step). Round-11 = round-10 resubmitted
// (infra failure, no result). Deltas vs round 9 (L3 tail cut):
//  - GS mix in packed f16 (pkrtz th pairs -> 50 v_pk_fma, direct b64 write;
//    state already passes through h16 every step — only 5-term sum precision
//    changes; raw-state->xs stays exact f32)
//  - tanh: th = fma(-2, rcp(E+1), 1)  (6 ops, sign-correct)
//  - setprio(1) scoped to L3 MFMA chain only (prio 0 during tanh/mix so the
//    co-resident block's MFMA wins issue during our VALU tail)
// __launch_bounds__(256,2) => 128-VGPR cap (empirical: rounds 0-1, 5-9).
// ---------------------------------------------------------------------------
__global__ __launch_bounds__(256, 2) void rnn_kernel(
    const float* __restrict__ x, const float* __restrict__ adj,
    const float* __restrict__ W0, const float* __restrict__ b0,
    const float* __restrict__ W1, const float* __restrict__ b1,
    const float* __restrict__ W2, const float* __restrict__ b2,
    float* __restrict__ xs)
{
    __shared__ __align__(16) h16 sGD[2][MR*128]; // 40960 B (L1 out / L2 out)
    __shared__ __align__(16) h16 sGS[MR*64];     // 10240 B (state, mixed)
    __shared__ h16  sx[2][TB][NODE][16];         // 10240 B (x chunks, dbuf)
    __shared__ h16  sxg[TB][MR];                 //  5120 B (mixed x, f16)

    const int tid  = threadIdx.x;
    const int lane = tid & 63;
    const int w    = tid >> 6;       // wave 0..3
    const int ln   = lane & 15;      // col = batch elem e
    const int q    = lane >> 4;      // quad 0..3
    const int k0q  = q*8;
    const int bbase = blockIdx.x * NB;

    // ---- persistent LDS byte-bases (see swizzle recap above) ----
    char* const gd0 = (char*)&sGD[0][0];
    char* const gsB = (char*)&sGS[0];
    const int xorv = (ln & 7) << 3;
    const int rB0 = ln*256 + 2*(( 0 + k0q) ^ xorv);  // GD read, ks even (ks>=2: +128)
    const int rB1 = ln*256 + 2*((32 + k0q) ^ xorv);  // GD read, ks odd
    const int gR0 = ln*128 + 2*(( 0 + k0q) ^ xorv);  // GS read, a0
    const int gR1 = ln*128 + 2*((32 + k0q) ^ xorv);  // GS read, a1
    const int wB0 = ln*256 + 2*(((2*w+0)*16 + q*4) ^ xorv);  // GD write t2=0
    const int wB1 = ln*256 + 2*(((2*w+1)*16 + q*4) ^ xorv);  // GD write t2=1
    const int gW  = ln*128 + 2*((w*16 + q*4) ^ xorv);        // GS write

    // ---- A = adj.T, wave-uniform -> SGPRs (f32 + packed f16 copies) ----
    float  af[NODE][NODE];
    half2v ahp[NODE][NODE];
    #pragma unroll
    for (int i = 0; i < NODE; ++i)
        #pragma unroll
        for (int j = 0; j < NODE; ++j) {
            float v = rfl_f(adj[j*NODE + i]);
            af[i][j] = v;
            h16 hv = (h16)v;
            half2v t; t[0] = hv; t[1] = hv;
            ahp[i][j] = t;
        }

    // ---- weight fragments (VGPRs): two 16-feat tiles per wave (L1/L2),
    //      one (L3). A-frag of W^T: lane holds W[ks*32+q*8+j][feat tile]. ----
    half8 wf0[2][2], wf0x[2], wf1f[2][4], wf3[4];
    {
        #pragma unroll
        for (int t2 = 0; t2 < 2; ++t2) {
            int n1 = (2*w+t2)*16 + ln;
            #pragma unroll
            for (int ks = 0; ks < 2; ++ks) {
                half8 f;
                #pragma unroll
                for (int j = 0; j < 8; ++j)
                    f[j] = (h16)W0[(size_t)(1 + ks*32 + k0q + j)*128 + n1]; // rows 1..64
                wf0[t2][ks] = f;
            }
            // x-block A-frag: k-slot 64 (q==0, j==0) = W0 row 0, else 0
            {
                half8 f;
                #pragma unroll
                for (int j = 0; j < 8; ++j) f[j] = (h16)0.f;
                if (q == 0) f[0] = (h16)W0[n1];
                wf0x[t2] = f;
            }
            #pragma unroll
            for (int ks = 0; ks < 4; ++ks) {
                half8 f;
                #pragma unroll
                for (int j = 0; j < 8; ++j)
                    f[j] = (h16)W1[(size_t)(ks*32 + k0q + j)*128 + n1];
                wf1f[t2][ks] = f;
            }
        }
        int n3 = w*16 + ln;
        #pragma unroll
        for (int ks = 0; ks < 4; ++ks) {
            half8 f;
            #pragma unroll
            for (int j = 0; j < 8; ++j)
                f[j] = (h16)W2[(size_t)(ks*32 + k0q + j)*64 + n3];
            wf3[ks] = f;
        }
    }
    // Bias quads (MFMA C-operand init), per out-feature.
    float4v b0q[2], b1q[2], b2q;
    #pragma unroll
    for (int t2 = 0; t2 < 2; ++t2)
        #pragma unroll
        for (int r = 0; r < 4; ++r) {
            int fi = (2*w+t2)*16 + q*4 + r;
            b0q[t2][r] = b0[fi];
            b1q[t2][r] = b1[fi];
        }
    #pragma unroll
    for (int r = 0; r < 4; ++r) b2q[r] = b2[w*16 + q*4 + r];

    // ---- prologue: stage x chunk 0, zero initial mixed state ----
    for (int i = tid; i < TB*NODE*16; i += 256) {
        int tl = i & 31; int ne = i >> 5; int n = ne >> 4; int e = ne & 15;
        sx[0][tl][n][e] = (h16)x[((size_t)(bbase+e)*NODE + n)*TT + tl];
    }
    for (int i = tid; i < MR*64; i += 256) sGS[i] = (h16)0.f;
    __syncthreads();

    #pragma unroll 1
    for (int tc = 0; tc < TT/TB; ++tc) {
        const int buf = tc & 1;
        // mixed x for this chunk (f16): sxg[ti][nd*16+e] = sum_j af[nd][j]*x
        for (int i = tid; i < TB*MR; i += 256) {
            int ti = i / MR, row = i - ti*MR;
            int nd = row >> 4, e = row & 15;
            float acc = 0.f;
            #pragma unroll
            for (int j = 0; j < NODE; ++j)
                acc += af[nd][j] * (float)sx[buf][ti][j][e];
            sxg[ti][row] = (h16)acc;
        }
        if (tc+1 < TT/TB) {   // stage next chunk (other buffer)
            for (int i = tid; i < TB*NODE*16; i += 256) {
                int tl = i & 31; int ne = i >> 5; int n = ne >> 4; int e = ne & 15;
                sx[buf^1][tl][n][e] =
                    (h16)x[((size_t)(bbase+e)*NODE + n)*TT + (tc+1)*TB + tl];
            }
        }
        __syncthreads();

        #pragma unroll 1
        for (int tt = 0; tt < TB; ++tt) {
            const int t = tc*TB + tt;
            // -------- L1 + mix: G1 = A @ relu([x|gS] W0 + b0) -------------
            {
                half2v g[2][NODE][2];
                __builtin_amdgcn_s_setprio(1);
                #pragma unroll
                for (int nd = 0; nd < NODE; ++nd) {
                    half8 a0 = *(const half8*)(gsB + gR0 + nd*2048);
                    half8 a1 = *(const half8*)(gsB + gR1 + nd*2048);
                    // B-frag for the x k-block: slot 64 (q==0,j==0) = xg
                    h16 xgv = sxg[tt][nd*16 + ln];
                    half8 a2;
                    #pragma unroll
                    for (int j = 0; j < 8; ++j) a2[j] = (h16)0.f;
                    if (q == 0) a2[0] = xgv;
                    #pragma unroll
                    for (int t2 = 0; t2 < 2; ++t2) {
                        float4v acc = __builtin_amdgcn_mfma_f32_16x16x32_f16(wf0x[t2], a2, b0q[t2], 0,0,0);
                        acc = __builtin_amdgcn_mfma_f32_16x16x32_f16(wf0[t2][0], a0, acc, 0,0,0);
                        acc = __builtin_amdgcn_mfma_f32_16x16x32_f16(wf0[t2][1], a1, acc, 0,0,0);
                        half2v p0 = pkmax0(pkrtz(acc[0], acc[1]));
                        half2v p1 = pkmax0(pkrtz(acc[2], acc[3]));
                        if (nd == 0) {
                            #pragma unroll
                            for (int i = 0; i < NODE; ++i) {
                                g[t2][i][0] = ahp[i][0]*p0;
                                g[t2][i][1] = ahp[i][0]*p1;
                            }
                        } else {
                            #pragma unroll
                            for (int i = 0; i < NODE; ++i) {
                                g[t2][i][0] += ahp[i][nd]*p0;
                                g[t2][i][1] += ahp[i][nd]*p1;
                            }
                        }
                    }
                }
                __builtin_amdgcn_s_setprio(0);
                #pragma unroll
                for (int t2 = 0; t2 < 2; ++t2)
                    #pragma unroll
                    for (int i = 0; i < NODE; ++i) {
                        h16x4 o;
                        o[0]=g[t2][i][0][0]; o[1]=g[t2][i][0][1];
                        o[2]=g[t2][i][1][0]; o[3]=g[t2][i][1][1];
                        *(h16x4*)(gd0 + (t2 ? wB1 : wB0) + i*4096) = o;
                    }
            }
            __syncthreads();
            // -------- L2 + mix: G2 = A @ relu(G1 W1 + b1) -----------------
            {
                half2v g[2][NODE][2];
                __builtin_amdgcn_s_setprio(1);
                #pragma unroll
                for (int nd = 0; nd < NODE; ++nd) {
                    half8 a[4];
                    a[0] = *(const half8*)(gd0 + rB0 +       nd*4096);
                    a[1] = *(const half8*)(gd0 + rB1 +       nd*4096);
                    a[2] = *(const half8*)(gd0 + rB0 + 128 + nd*4096);
                    a[3] = *(const half8*)(gd0 + rB1 + 128 + nd*4096);
                    #pragma unroll
                    for (int t2 = 0; t2 < 2; ++t2) {
                        float4v acc = __builtin_amdgcn_mfma_f32_16x16x32_f16(wf1f[t2][0], a[0], b1q[t2], 0,0,0);
                        #pragma unroll
                        for (int ks = 1; ks < 4; ++ks)
                            acc = __builtin_amdgcn_mfma_f32_16x16x32_f16(wf1f[t2][ks], a[ks], acc, 0,0,0);
                        half2v p0 = pkmax0(pkrtz(acc[0], acc[1]));
                        half2v p1 = pkmax0(pkrtz(acc[2], acc[3]));
                        if (nd == 0) {
                            #pragma unroll
                            for (int i = 0; i < NODE; ++i) {
                                g[t2][i][0] = ahp[i][0]*p0;
                                g[t2][i][1] = ahp[i][0]*p1;
                            }
                        } else {
                            #pragma unroll
                            for (int i = 0; i < NODE; ++i) {
                                g[t2][i][0] += ahp[i][nd]*p0;
                                g[t2][i][1] += ahp[i][nd]*p1;
                            }
                        }
                    }
                }
                __builtin_amdgcn_s_setprio(0);
                #pragma unroll
                for (int t2 = 0; t2 < 2; ++t2)
                    #pragma unroll
                    for (int i = 0; i < NODE; ++i) {
                        h16x4 o;
                        o[0]=g[t2][i][0][0]; o[1]=g[t2][i][0][1];
                        o[2]=g[t2][i][1][0]; o[3]=g[t2][i][1][1];
                        *(h16x4*)(gd0 + 20480 + (t2 ? wB1 : wB0) + i*4096) = o;
                    }
            }
            __syncthreads();
            // -------- L3 + mix: state = tanh(G2 W2 + b2); GS = A @ state --
            {
                const bool last = (t == TT-1);
                half2v gp[NODE][2];
                #pragma unroll
                for (int nd = 0; nd < NODE; ++nd) {
                    half8 a[4];
                    a[0] = *(const half8*)(gd0 + 20480 + rB0 +       nd*4096);
                    a[1] = *(const half8*)(gd0 + 20480 + rB1 +       nd*4096);
                    a[2] = *(const half8*)(gd0 + 20480 + rB0 + 128 + nd*4096);
                    a[3] = *(const half8*)(gd0 + 20480 + rB1 + 128 + nd*4096);
                    __builtin_amdgcn_s_setprio(1);
                    float4v acc = __builtin_amdgcn_mfma_f32_16x16x32_f16(wf3[0], a[0], b2q, 0,0,0);
                    #pragma unroll
                    for (int ks = 1; ks < 4; ++ks)
                        acc = __builtin_amdgcn_mfma_f32_16x16x32_f16(wf3[ks], a[ks], acc, 0,0,0);
                    __builtin_amdgcn_s_setprio(0);
                    float th[4];
                    #pragma unroll
                    for (int r = 0; r < 4; ++r) {
                        // tanh(z) = 1 - 2/(E+1), E = 2^(2*log2e*clamp(z,±9))
                        float zc = __builtin_amdgcn_fmed3f(acc[r], -9.f, 9.f);
                        float E  = __builtin_amdgcn_exp2f(zc * 2.885390082f);
                        float rc = __builtin_amdgcn_rcpf(E + 1.f);
                        th[r] = fmaf(-2.f, rc, 1.f);
                    }
                    if (last) {   // raw state straight to xs (once, exact f32)
                        size_t ob = (size_t)(bbase+ln)*XS_DIM + 5 + nd*64 + w*16 + q*4;
                        #pragma unroll
                        for (int r = 0; r < 4; ++r) xs[ob + r] = th[r];
                    }
                    half2v p0 = pkrtz(th[0], th[1]);
                    half2v p1 = pkrtz(th[2], th[3]);
                    if (nd == 0) {
                        #pragma unroll
                        for (int i = 0; i < NODE; ++i) {
                            gp[i][0] = ahp[i][0]*p0;
                            gp[i][1] = ahp[i][0]*p1;
                        }
                    } else {
                        #pragma unroll
                        for (int i = 0; i < NODE; ++i) {
                            gp[i][0] += ahp[i][nd]*p0;
                            gp[i][1] += ahp[i][nd]*p1;
                        }
                    }
                }
                #pragma unroll
                for (int i = 0; i < NODE; ++i) {
                    h16x4 o;
                    o[0]=gp[i][0][0]; o[1]=gp[i][0][1];
                    o[2]=gp[i][1][0]; o[3]=gp[i][1][1];
                    *(h16x4*)(gsB + gW + i*2048) = o;
                }
            }
            __syncthreads();
        }
    }

    // ---- epilogue: x_end -> xs[b][0..4] ----
    if (tid < NB*NODE) {
        int e = tid / NODE, j = tid - (tid/NODE)*NODE;
        xs[(size_t)(bbase+e)*XS_DIM + j] = (float)sx[1][TB-1][j][e];   // t=511
    }
}

// ---------------------------------------------------------------------------
// Kernel B: h = relu(xs @ fc1_w + fc1_b) + per-column sum/sumsq for BN.
// ---------------------------------------------------------------------------
__global__ __launch_bounds__(256) void fc1_kernel(
    const float* __restrict__ xs, const float* __restrict__ fc1_w,
    const float* __restrict__ fc1_b, float* __restrict__ h,
    float* __restrict__ sums)
{
    __shared__ float s_xs[16*XS_DIM];
    const int tid = threadIdx.x;
    const int r0 = blockIdx.x * 16;
    for (int i = tid; i < 16*XS_DIM; i += 256)
        s_xs[i] = xs[(size_t)r0*XS_DIM + i];
    __syncthreads();

    float acc[16];
    #pragma unroll
    for (int r = 0; r < 16; ++r) acc[r] = 0.f;
    for (int k = 0; k < XS_DIM; ++k) {
        float wv = fc1_w[(size_t)k*H2 + tid];
        #pragma unroll
        for (int r = 0; r < 16; ++r) acc[r] += s_xs[r*XS_DIM + k]*wv;
    }
    float bb = fc1_b[tid];
    float ls = 0.f, lq = 0.f;
    #pragma unroll
    for (int r = 0; r < 16; ++r) {
        float v = fmaxf(acc[r] + bb, 0.f);
        h[(size_t)(r0+r)*H2 + tid] = v;
        ls += v; lq += v*v;
    }
    atomicAdd(&sums[tid], ls);
    atomicAdd(&sums[H2 + tid], lq);
}

// ---------------------------------------------------------------------------
// Kernel C: BN(train) normalize + fc2 + softmax. One wave per row.
// ---------------------------------------------------------------------------
__global__ __launch_bounds__(256) void head_kernel(
    const float* __restrict__ h, const float* __restrict__ sums,
    const float* __restrict__ gamma, const float* __restrict__ beta,
    const float* __restrict__ fc2_w, const float* __restrict__ fc2_b,
    float* __restrict__ out)
{
    const int lane = threadIdx.x & 63;
    const int r = blockIdx.x*4 + (threadIdx.x >> 6);
    const int c0 = lane*4;

    float4 hv = *(const float4*)&h[(size_t)r*H2 + c0];
    float hvv[4] = {hv.x, hv.y, hv.z, hv.w};
    float y[4];
    #pragma unroll
    for (int c = 0; c < 4; ++c) {
        int cc = c0 + c;
        float mean = sums[cc] * (1.f/NBATCH);
        float var  = sums[H2+cc]*(1.f/NBATCH) - mean*mean;
        float rstd = rsqrtf(var + EPS);
        y[c] = (hvv[c] - mean)*rstd*gamma[cc] + beta[cc];
    }
    float lg[7];
    #pragma unroll
    for (int j = 0; j < 7; ++j) {
        float p = 0.f;
        #pragma unroll
        for (int c = 0; c < 4; ++c) p += y[c]*fc2_w[(size_t)(c0+c)*7 + j];
        #pragma unroll
        for (int off = 32; off >= 1; off >>= 1) p += __shfl_xor(p, off, 64);
        lg[j] = p + fc2_b[j];
    }
    if (lane == 0) {
        float m = lg[0];
        #pragma unroll
        for (int j = 1; j < 7; ++j) m = fmaxf(m, lg[j]);
        float ev[7]; float s = 0.f;
        #pragma unroll
        for (int j = 0; j < 7; ++j) { ev[j] = expf(lg[j]-m); s += ev[j]; }
        float inv = 1.f/s;
        #pragma unroll
        for (int j = 0; j < 7; ++j) out[(size_t)r*7 + j] = ev[j]*inv;
    }
}

// ---------------------------------------------------------------------------
extern "C" void kernel_launch(void* const* d_in, const int* in_sizes, int n_in,
                              void* d_out, int out_size, void* d_ws, size_t ws_size,
                              hipStream_t stream)
{
    (void)in_sizes; (void)n_in; (void)out_size; (void)ws_size;
    const float* x     = (const float*)d_in[0];
    const float* adj   = (const float*)d_in[1];
    const float* W0    = (const float*)d_in[2];
    const float* b0    = (const float*)d_in[3];
    const float* W1    = (const float*)d_in[4];
    const float* b1    = (const float*)d_in[5];
    const float* W2    = (const float*)d_in[6];
    const float* b2    = (const float*)d_in[7];
    const float* fc1w  = (const float*)d_in[8];
    const float* fc1b  = (const float*)d_in[9];
    const float* gamma = (const float*)d_in[10];
    const float* beta  = (const float*)d_in[11];
    const float* fc2w  = (const float*)d_in[12];
    const float* fc2b  = (const float*)d_in[13];
    float* out = (float*)d_out;

    char* ws = (char*)d_ws;
    float* xs   = (float*)(ws);                                  // 8192*325 f32
    float* hbuf = (float*)(ws + 10649600);                       // 8192*256 f32
    float* sums = (float*)(ws + 10649600 + 8388608);             // 512 f32

    hipMemsetAsync(sums, 0, 512*sizeof(float), stream);
    rnn_kernel<<<NBATCH/NB, 256, 0, stream>>>(x, adj, W0, b0, W1, b1, W2, b2, xs);
    fc1_kernel<<<NBATCH/16, 256, 0, stream>>>(xs, fc1w, fc1b, hbuf, sums);
    head_kernel<<<NBATCH/4, 256, 0, stream>>>(hbuf, sums, gamma, beta, fc2w, fc2b, out);
}